// Round 2
// baseline (1710.230 us; speedup 1.0000x reference)
//
#include <hip/hip_runtime.h>
#include <math.h>

// Model constants (shapes from reference)
static constexpr int HID = 128;
static constexpr int H   = 8;
static constexpr int DH  = 16;
static constexpr int LAY = 4;
static constexpr int K   = 100;

__device__ __forceinline__ float leaky(float x){ return fmaxf(x, 0.2f*x); }
__device__ __forceinline__ float elu1(float x){ return x > 0.f ? x : expm1f(x); }

// ---------------- utility ----------------
__global__ void k_zero(int* p, int n){
  int i = blockIdx.x*blockDim.x + threadIdx.x;
  if (i < n) p[i] = 0;
}

// ---------------- CSR build (counting sort by dst) ----------------
__global__ void k_deg(const int* __restrict__ dst, int* __restrict__ deg, int E){
  int e = blockIdx.x*blockDim.x + threadIdx.x;
  if (e < E) atomicAdd(&deg[dst[e]], 1);
}

// chunked scan: 1024 elems/block, 256 threads x 4
__global__ void k_scan1(const int* __restrict__ deg, int* __restrict__ row_ptr,
                        int* __restrict__ bsum, int n){
  __shared__ int s[256];
  int tid = threadIdx.x;
  int base = blockIdx.x*1024 + tid*4;
  int v0 = (base+0 < n) ? deg[base+0] : 0;
  int v1 = (base+1 < n) ? deg[base+1] : 0;
  int v2 = (base+2 < n) ? deg[base+2] : 0;
  int v3 = (base+3 < n) ? deg[base+3] : 0;
  int t1 = v0+v1, t2 = t1+v2, t3 = t2+v3;
  s[tid] = t3;
  __syncthreads();
  for (int off=1; off<256; off<<=1){
    int t = (tid >= off) ? s[tid-off] : 0;
    __syncthreads();
    s[tid] += t;
    __syncthreads();
  }
  int excl = tid ? s[tid-1] : 0;
  if (base+0 < n) row_ptr[1+base+0] = excl + v0;
  if (base+1 < n) row_ptr[1+base+1] = excl + t1;
  if (base+2 < n) row_ptr[1+base+2] = excl + t2;
  if (base+3 < n) row_ptr[1+base+3] = excl + t3;
  if (tid == 255) bsum[blockIdx.x] = s[255];
}

__global__ void k_scan2(int* bsum, int nb){
  if (threadIdx.x == 0 && blockIdx.x == 0){
    int run = 0;
    for (int i=0;i<nb;i++){ int t = bsum[i]; bsum[i] = run; run += t; }
  }
}

__global__ void k_scan3(int* row_ptr, const int* __restrict__ bsum, int n){
  int i = blockIdx.x*blockDim.x + threadIdx.x;
  if (i < n) row_ptr[1+i] += bsum[i >> 10];
  if (i == 0) row_ptr[0] = 0;
}

__global__ void k_scatter(const int* __restrict__ src, const int* __restrict__ dst,
                          const int* __restrict__ row_ptr, int* __restrict__ fill,
                          int* __restrict__ srcs, int E){
  int e = blockIdx.x*blockDim.x + threadIdx.x;
  if (e < E){
    int d = dst[e];
    int pos = row_ptr[d] + atomicAdd(&fill[d], 1);
    srcs[pos] = src[e];
  }
}

// ---------------- fused xl/xr GEMM: [N,128] @ [128,128] x2 ----------------
// 256 threads: tid>>7 selects {wl,wr}, tid&127 = output column. 32-row tile.
// x reads are WAVE-UNIFORM (address from blockIdx + loop vars only) -> the
// compiler scalarizes them to s_load (constant cache, scalar pipe), so the
// inner loop is pure v_fma on the vector pipe. No LDS, no barrier.
__global__ __launch_bounds__(256) void k_gemm2(const float* __restrict__ x,
    const float* __restrict__ wl, const float* __restrict__ wr,
    float* __restrict__ xl, float* __restrict__ xr, int nrows){
  int tid = threadIdx.x;
  int row0 = blockIdx.x * 32;
  int g = tid >> 7;          // 0 -> wl, 1 -> wr
  int c = tid & 127;
  const float* w = g ? wr : wl;
  const float4* x4 = reinterpret_cast<const float4*>(x);
  float acc[32];
  #pragma unroll
  for (int r=0;r<32;r++) acc[r] = 0.f;
  const int xbase = row0 * 32;     // float4 index of (row0, k=0)
  for (int k4 = 0; k4 < 32; ++k4){
    float w0 = w[(4*k4+0)*128 + c];
    float w1 = w[(4*k4+1)*128 + c];
    float w2 = w[(4*k4+2)*128 + c];
    float w3 = w[(4*k4+3)*128 + c];
    #pragma unroll
    for (int r=0;r<32;r++){
      float4 xv = x4[xbase + r*32 + k4];   // uniform -> s_load_dwordx4
      acc[r] = fmaf(xv.w, w3, fmaf(xv.z, w2, fmaf(xv.y, w1, fmaf(xv.x, w0, acc[r]))));
    }
  }
  float* out = g ? xr : xl;
  #pragma unroll
  for (int r=0;r<32;r++){
    int row = row0 + r;
    if (row < nrows) out[row*128 + c] = acc[r];
  }
}

// ---------------- GATv2 edge pass: one wave per dst node, 2 edges/iter ----
// Half-wave hw (lane>>5) owns edge p+hw; lane sl=lane&31 owns feature dims
// 4sl..4sl+3 (head h = sl>>2 spans 4 lanes -> 2 shfl_xor hops for the score).
// Softmax in log2 domain (att pre-scaled by log2 e), defer-max with THR=8:
// rescale only when __any(e - m > 8) -- rare, so the common path is a single
// v_exp_f32 + 5 fma per edge-pair-lane. Flash-merge of the two half-wave
// states once per node at the end.
__global__ __launch_bounds__(256) void k_gat(const float* __restrict__ xl,
    const float* __restrict__ xr, const int* __restrict__ row_ptr,
    const int* __restrict__ srcs, const float* __restrict__ att,
    const float* __restrict__ bias, float* __restrict__ xout, int n){
  int wid  = (blockIdx.x * blockDim.x + threadIdx.x) >> 6;
  int lane = threadIdx.x & 63;
  if (wid >= n) return;
  int hw = lane >> 5;
  int sl = lane & 31;
  const float4* xl4 = reinterpret_cast<const float4*>(xl);
  float4 xrv = reinterpret_cast<const float4*>(xr)[wid*32 + sl];
  constexpr float L2E = 1.44269504f;
  float4 av = reinterpret_cast<const float4*>(att)[sl];
  float a0 = av.x*L2E, a1 = av.y*L2E, a2 = av.z*L2E, a3 = av.w*L2E;
  float m = 0.f, ssum = 0.f;
  float ac0 = 0.f, ac1 = 0.f, ac2 = 0.f, ac3 = 0.f;
  int start = row_ptr[wid], end = row_ptr[wid+1];
  for (int p = start; p < end; p += 2){
    int s0 = srcs[p];                                // uniform -> s_load
    int s1 = (p+1 < end) ? srcs[p+1] : s0;
    int sidx = hw ? s1 : s0;
    bool valid = (p + hw) < end;
    float4 v = xl4[sidx*32 + sl];
    float e = fmaf(a3, leaky(v.w+xrv.w), fmaf(a2, leaky(v.z+xrv.z),
              fmaf(a1, leaky(v.y+xrv.y), a0*leaky(v.x+xrv.x))));
    e += __shfl_xor(e, 1);
    e += __shfl_xor(e, 2);                            // head score in 4 lanes
    if (!valid) e = -INFINITY;
    if (__any(e - m > 8.f)){                          // rare rescale
      float mn = fmaxf(m, e);
      float sc = __builtin_amdgcn_exp2f(m - mn);
      ssum *= sc; ac0 *= sc; ac1 *= sc; ac2 *= sc; ac3 *= sc;
      m = mn;
    }
    float pr = __builtin_amdgcn_exp2f(e - m);         // 0 for invalid lane
    ssum += pr;
    ac0 = fmaf(pr, v.x, ac0);
    ac1 = fmaf(pr, v.y, ac1);
    ac2 = fmaf(pr, v.z, ac2);
    ac3 = fmaf(pr, v.w, ac3);
  }
  // flash-merge the two half-wave partial states (same dims, disjoint edges)
  float mo = __shfl_xor(m, 32);
  float so = __shfl_xor(ssum, 32);
  float b0 = __shfl_xor(ac0, 32), b1 = __shfl_xor(ac1, 32),
        b2 = __shfl_xor(ac2, 32), b3 = __shfl_xor(ac3, 32);
  float mm = fmaxf(m, mo);
  float sca = __builtin_amdgcn_exp2f(m - mm);
  float scb = __builtin_amdgcn_exp2f(mo - mm);
  ssum = ssum*sca + so*scb;
  ac0 = ac0*sca + b0*scb;  ac1 = ac1*sca + b1*scb;
  ac2 = ac2*sca + b2*scb;  ac3 = ac3*sca + b3*scb;
  float o0=0.f, o1=0.f, o2=0.f, o3=0.f;
  if (end > start){
    float inv = 1.f/ssum;
    o0 = ac0*inv; o1 = ac1*inv; o2 = ac2*inv; o3 = ac3*inv;
  }
  float4 bv = reinterpret_cast<const float4*>(bias)[sl];
  float4 outv = make_float4(elu1(o0+bv.x), elu1(o1+bv.y),
                            elu1(o2+bv.z), elu1(o3+bv.w));
  reinterpret_cast<float4*>(xout)[wid*32 + sl] = outv;
}

// ---------------- graph node ranges (batch is sorted) ----------------
__global__ void k_graph_ptr(const int* __restrict__ batch, int* __restrict__ gp,
                            int n, int nb){
  int b = blockIdx.x*blockDim.x + threadIdx.x;
  if (b > nb) return;
  int lo = 0, hi = n;
  while (lo < hi){ int mid = (lo+hi)>>1; if (batch[mid] < b) lo = mid+1; else hi = mid; }
  gp[b] = lo;   // for b==nb this yields n
}

// ---------------- gated sum-pool + max-pool: one wave per graph ----------------
__global__ __launch_bounds__(256) void k_pool(const float* __restrict__ x,
    const int* __restrict__ gp, const float* __restrict__ read_w,
    const float* __restrict__ read_b, float* __restrict__ mol, int nb){
  int w    = (blockIdx.x * blockDim.x + threadIdx.x) >> 6;
  int lane = threadIdx.x & 63;
  if (w >= nb) return;
  const float2* x2 = reinterpret_cast<const float2*>(x);
  float rw0 = read_w[2*lane], rw1 = read_w[2*lane+1];
  float rb = read_b[0];
  float s0=0.f, s1=0.f, m0=-INFINITY, m1=-INFINITY;
  int start = gp[w], end = gp[w+1];
  for (int nidx = start; nidx < end; ++nidx){
    float2 v = x2[nidx*64 + lane];
    float d = v.x*rw0 + v.y*rw1;
    d += __shfl_xor(d, 1);  d += __shfl_xor(d, 2);  d += __shfl_xor(d, 4);
    d += __shfl_xor(d, 8);  d += __shfl_xor(d, 16); d += __shfl_xor(d, 32);
    float gate = 1.f/(1.f + expf(-(d + rb)));
    s0 += gate*v.x;  s1 += gate*v.y;
    m0 = fmaxf(m0, v.x);  m1 = fmaxf(m1, v.y);
  }
  if (end <= start){ m0 = 0.f; m1 = 0.f; }   // empty graph: isfinite guard
  mol[w*256 + 2*lane]       = s0;
  mol[w*256 + 2*lane+1]     = s1;
  mol[w*256 + 128 + 2*lane]   = m0;
  mol[w*256 + 128 + 2*lane+1] = m1;
}

// ---------------- Boltzmann + MLP head: one block (128 thr) per graph ----------------
__global__ __launch_bounds__(128) void k_head(const float* __restrict__ mol,
    const float* __restrict__ temps, const float* __restrict__ en_w,
    const float* __restrict__ en_b, const float* __restrict__ w1,
    const float* __restrict__ b1, const float* __restrict__ w2,
    const float* __restrict__ b2, float* __restrict__ out, int nb){
  __shared__ float molS[256];
  __shared__ float red[128];
  __shared__ float distS[128];
  __shared__ float hS[64];
  int b = blockIdx.x, tid = threadIdx.x;
  if (b >= nb) return;
  molS[tid]       = mol[b*256 + tid];
  molS[tid + 128] = mol[b*256 + 128 + tid];
  __syncthreads();
  float z = -INFINITY;
  if (tid < K){
    float acc = en_b[tid];
    for (int j=0;j<256;j++) acc += molS[j]*en_w[j*K + tid];
    z = -acc / temps[b];
  }
  red[tid] = z; __syncthreads();
  for (int off=64; off>0; off>>=1){
    if (tid < off) red[tid] = fmaxf(red[tid], red[tid+off]);
    __syncthreads();
  }
  float mx = red[0]; __syncthreads();
  float ex = (tid < K) ? expf(z - mx) : 0.f;
  red[tid] = ex; __syncthreads();
  for (int off=64; off>0; off>>=1){
    if (tid < off) red[tid] += red[tid+off];
    __syncthreads();
  }
  float denom = red[0];
  distS[tid] = ex / denom;
  __syncthreads();
  if (tid < 64){
    float acc = b1[tid];
    for (int k=0;k<K;k++) acc += distS[k]*w1[k*64 + tid];
    hS[tid] = elu1(acc);
  }
  __syncthreads();
  red[tid] = (tid < 64) ? hS[tid]*w2[tid] : 0.f;
  __syncthreads();
  for (int off=32; off>0; off>>=1){
    if (tid < off) red[tid] += red[tid+off];
    __syncthreads();
  }
  if (tid == 0) out[b] = red[0] + b2[0];
}

// ---------------- launch ----------------
extern "C" void kernel_launch(void* const* d_in, const int* in_sizes, int n_in,
                              void* d_out, int out_size, void* d_ws, size_t ws_size,
                              hipStream_t stream){
  const float* x0    = (const float*)d_in[0];
  const int*   ei    = (const int*)  d_in[1];
  const int*   batch = (const int*)  d_in[2];
  const float* temps = (const float*)d_in[3];
  const float* wl    = (const float*)d_in[4];
  const float* wr    = (const float*)d_in[5];
  const float* att   = (const float*)d_in[6];
  const float* gatb  = (const float*)d_in[7];
  const float* read_w= (const float*)d_in[8];
  const float* read_b= (const float*)d_in[9];
  const float* en_w  = (const float*)d_in[10];
  const float* en_b  = (const float*)d_in[11];
  const float* w1    = (const float*)d_in[12];
  const float* b1    = (const float*)d_in[13];
  const float* w2    = (const float*)d_in[14];
  const float* b2    = (const float*)d_in[15];
  float* out = (float*)d_out;

  const int N = in_sizes[0] / HID;
  const int E = in_sizes[1] / 2;
  const int B = in_sizes[3];
  const int* src = ei;
  const int* dst = ei + E;

  char* ws = (char*)d_ws;
  size_t off = 0;
  auto alloc = [&](size_t bytes)->char*{
    char* p = ws + off; off += (bytes + 255) & ~size_t(255); return p;
  };
  float* xl    = (float*)alloc(sizeof(float)*(size_t)N*HID);
  float* xr    = (float*)alloc(sizeof(float)*(size_t)N*HID);
  float* xb    = (float*)alloc(sizeof(float)*(size_t)N*HID);
  float* mol   = (float*)alloc(sizeof(float)*(size_t)B*2*HID);
  int* row_ptr = (int*)alloc(sizeof(int)*(size_t)(N+1));
  int* deg     = (int*)alloc(sizeof(int)*(size_t)N);
  int* fill    = (int*)alloc(sizeof(int)*(size_t)N);
  int* srcs    = (int*)alloc(sizeof(int)*(size_t)E);
  int* bsum    = (int*)alloc(sizeof(int)*1024);
  int* gp      = (int*)alloc(sizeof(int)*(size_t)(B+1));

  // --- CSR by dst (once per call; reused by all 4 layers) ---
  int nchunk = (N + 1023) / 1024;
  k_zero<<<(N+255)/256, 256, 0, stream>>>(deg, N);
  k_zero<<<(N+255)/256, 256, 0, stream>>>(fill, N);
  k_deg<<<(E+255)/256, 256, 0, stream>>>(dst, deg, E);
  k_scan1<<<nchunk, 256, 0, stream>>>(deg, row_ptr, bsum, N);
  k_scan2<<<1, 1, 0, stream>>>(bsum, nchunk);
  k_scan3<<<(N+255)/256, 256, 0, stream>>>(row_ptr, bsum, N);
  k_scatter<<<(E+255)/256, 256, 0, stream>>>(src, dst, row_ptr, fill, srcs, E);

  // --- 4 GATv2 layers ---
  const float* xin = x0;
  for (int l = 0; l < LAY; ++l){
    k_gemm2<<<(N+31)/32, 256, 0, stream>>>(xin, wl + (size_t)l*HID*HID,
                                           wr + (size_t)l*HID*HID, xl, xr, N);
    k_gat<<<(N+3)/4, 256, 0, stream>>>(xl, xr, row_ptr, srcs,
                                       att + (size_t)l*H*DH, gatb + (size_t)l*HID, xb, N);
    xin = xb;
  }

  // --- readout + head ---
  k_graph_ptr<<<(B+1+255)/256, 256, 0, stream>>>(batch, gp, N, B);
  k_pool<<<(B+3)/4, 256, 0, stream>>>(xb, gp, read_w, read_b, mol, B);
  k_head<<<B, 128, 0, stream>>>(mol, temps, en_w, en_b, w1, b1, w2, b2, out, B);
}

// Round 3
// 1379.051 us; speedup vs baseline: 1.2402x; 1.2402x over previous
//
#include <hip/hip_runtime.h>
#include <math.h>

// Model constants (shapes from reference)
static constexpr int HID = 128;
static constexpr int H   = 8;
static constexpr int DH  = 16;
static constexpr int LAY = 4;
static constexpr int K   = 100;

__device__ __forceinline__ float leaky(float x){ return fmaxf(x, 0.2f*x); }
__device__ __forceinline__ float elu1(float x){ return x > 0.f ? x : expm1f(x); }

// ---------------- utility ----------------
__global__ void k_zero(int* p, int n){
  int i = blockIdx.x*blockDim.x + threadIdx.x;
  if (i < n) p[i] = 0;
}

// ---------------- CSR build (counting sort by dst) ----------------
__global__ void k_deg(const int* __restrict__ dst, int* __restrict__ deg, int E){
  int e = blockIdx.x*blockDim.x + threadIdx.x;
  if (e < E) atomicAdd(&deg[dst[e]], 1);
}

// chunked scan: 1024 elems/block, 256 threads x 4
__global__ void k_scan1(const int* __restrict__ deg, int* __restrict__ row_ptr,
                        int* __restrict__ bsum, int n){
  __shared__ int s[256];
  int tid = threadIdx.x;
  int base = blockIdx.x*1024 + tid*4;
  int v0 = (base+0 < n) ? deg[base+0] : 0;
  int v1 = (base+1 < n) ? deg[base+1] : 0;
  int v2 = (base+2 < n) ? deg[base+2] : 0;
  int v3 = (base+3 < n) ? deg[base+3] : 0;
  int t1 = v0+v1, t2 = t1+v2, t3 = t2+v3;
  s[tid] = t3;
  __syncthreads();
  for (int off=1; off<256; off<<=1){
    int t = (tid >= off) ? s[tid-off] : 0;
    __syncthreads();
    s[tid] += t;
    __syncthreads();
  }
  int excl = tid ? s[tid-1] : 0;
  if (base+0 < n) row_ptr[1+base+0] = excl + v0;
  if (base+1 < n) row_ptr[1+base+1] = excl + t1;
  if (base+2 < n) row_ptr[1+base+2] = excl + t2;
  if (base+3 < n) row_ptr[1+base+3] = excl + t3;
  if (tid == 255) bsum[blockIdx.x] = s[255];
}

__global__ void k_scan2(int* bsum, int nb){
  if (threadIdx.x == 0 && blockIdx.x == 0){
    int run = 0;
    for (int i=0;i<nb;i++){ int t = bsum[i]; bsum[i] = run; run += t; }
  }
}

__global__ void k_scan3(int* row_ptr, const int* __restrict__ bsum, int n){
  int i = blockIdx.x*blockDim.x + threadIdx.x;
  if (i < n) row_ptr[1+i] += bsum[i >> 10];
  if (i == 0) row_ptr[0] = 0;
}

__global__ void k_scatter(const int* __restrict__ src, const int* __restrict__ dst,
                          const int* __restrict__ row_ptr, int* __restrict__ fill,
                          int* __restrict__ srcs, int E){
  int e = blockIdx.x*blockDim.x + threadIdx.x;
  if (e < E){
    int d = dst[e];
    int pos = row_ptr[d] + atomicAdd(&fill[d], 1);
    srcs[pos] = src[e];
  }
}

// ---------------- fused xl/xr GEMM: [N,128] @ [128,128] x2 ----------------
// Register-tiled: block = 256 threads (tx 0..15, ty 0..15) computes
// 128 rows x 64 cols for BOTH wl and wr (x read shared -> free 2x reuse).
// Per thread: 8 rows x 4 cols x 2 mats = 64 accumulators.
// Per k4-chunk (4 k): 8 ds_read_b128 + 8 L1-hit dwordx4 + 256 FMA-instr
// (~94% FMA density). x tile staged in LDS [128][16] float4 (32 KB, KC=64,
// two passes) with XOR swizzle col^(row>>3 & 3): read lanes = 4 distinct ty
// (4 distinct bank groups) x 16-lane broadcast -> conflict-free.
__global__ __launch_bounds__(256) void k_gemm2(const float* __restrict__ x,
    const float* __restrict__ wl, const float* __restrict__ wr,
    float* __restrict__ xl, float* __restrict__ xr, int nrows){
  __shared__ float4 xs[128][16];
  const int tid = threadIdx.x;
  const int tx = tid & 15, ty = tid >> 4;
  const int r0 = blockIdx.x * 128;
  const int c0 = blockIdx.y * 64 + tx * 4;
  const float4* x4 = reinterpret_cast<const float4*>(x);
  float4 accL[8], accR[8];           // [row i] -> 4 cols
  #pragma unroll
  for (int i=0;i<8;i++){
    accL[i] = make_float4(0.f,0.f,0.f,0.f);
    accR[i] = make_float4(0.f,0.f,0.f,0.f);
  }
  const int swz = ty & 3;
  for (int kk = 0; kk < 128; kk += 64){
    if (kk) __syncthreads();
    #pragma unroll
    for (int it = 0; it < 8; ++it){
      int idx = tid + it*256;
      int r = idx >> 4, k4 = idx & 15;
      float4 v = make_float4(0.f,0.f,0.f,0.f);
      if (r0 + r < nrows) v = x4[(size_t)(r0+r)*32 + (kk>>2) + k4];
      xs[r][k4 ^ ((r>>3)&3)] = v;
    }
    __syncthreads();
    for (int k4 = 0; k4 < 16; ++k4){
      const float* wlp = wl + (size_t)(kk + 4*k4)*128 + c0;
      const float* wrp = wr + (size_t)(kk + 4*k4)*128 + c0;
      float4 wl0 = *reinterpret_cast<const float4*>(wlp);
      float4 wl1 = *reinterpret_cast<const float4*>(wlp + 128);
      float4 wl2 = *reinterpret_cast<const float4*>(wlp + 256);
      float4 wl3 = *reinterpret_cast<const float4*>(wlp + 384);
      float4 wr0 = *reinterpret_cast<const float4*>(wrp);
      float4 wr1 = *reinterpret_cast<const float4*>(wrp + 128);
      float4 wr2 = *reinterpret_cast<const float4*>(wrp + 256);
      float4 wr3 = *reinterpret_cast<const float4*>(wrp + 384);
      const int kc = k4 ^ swz;
      #pragma unroll
      for (int i = 0; i < 8; ++i){
        float4 xv = xs[ty*8 + i][kc];
        accL[i].x = fmaf(xv.w, wl3.x, fmaf(xv.z, wl2.x, fmaf(xv.y, wl1.x, fmaf(xv.x, wl0.x, accL[i].x))));
        accL[i].y = fmaf(xv.w, wl3.y, fmaf(xv.z, wl2.y, fmaf(xv.y, wl1.y, fmaf(xv.x, wl0.y, accL[i].y))));
        accL[i].z = fmaf(xv.w, wl3.z, fmaf(xv.z, wl2.z, fmaf(xv.y, wl1.z, fmaf(xv.x, wl0.z, accL[i].z))));
        accL[i].w = fmaf(xv.w, wl3.w, fmaf(xv.z, wl2.w, fmaf(xv.y, wl1.w, fmaf(xv.x, wl0.w, accL[i].w))));
        accR[i].x = fmaf(xv.w, wr3.x, fmaf(xv.z, wr2.x, fmaf(xv.y, wr1.x, fmaf(xv.x, wr0.x, accR[i].x))));
        accR[i].y = fmaf(xv.w, wr3.y, fmaf(xv.z, wr2.y, fmaf(xv.y, wr1.y, fmaf(xv.x, wr0.y, accR[i].y))));
        accR[i].z = fmaf(xv.w, wr3.z, fmaf(xv.z, wr2.z, fmaf(xv.y, wr1.z, fmaf(xv.x, wr0.z, accR[i].z))));
        accR[i].w = fmaf(xv.w, wr3.w, fmaf(xv.z, wr2.w, fmaf(xv.y, wr1.w, fmaf(xv.x, wr0.w, accR[i].w))));
      }
    }
  }
  #pragma unroll
  for (int i = 0; i < 8; ++i){
    int row = r0 + ty*8 + i;
    if (row < nrows){
      *reinterpret_cast<float4*>(&xl[(size_t)row*128 + c0]) = accL[i];
      *reinterpret_cast<float4*>(&xr[(size_t)row*128 + c0]) = accR[i];
    }
  }
}

// ---------------- GATv2 edge pass: one wave per dst node, 2 edges/iter ----
// Half-wave hw (lane>>5) owns edge p+hw; lane sl=lane&31 owns feature dims
// 4sl..4sl+3 (head h = sl>>2 spans 4 lanes -> 2 shfl_xor hops for the score).
// Softmax in log2 domain (att pre-scaled by log2 e), defer-max with THR=8:
// rescale only when __any(e - m > 8) -- rare, so the common path is a single
// v_exp_f32 + 5 fma per edge-pair-lane. Flash-merge of the two half-wave
// states once per node at the end.
__global__ __launch_bounds__(256) void k_gat(const float* __restrict__ xl,
    const float* __restrict__ xr, const int* __restrict__ row_ptr,
    const int* __restrict__ srcs, const float* __restrict__ att,
    const float* __restrict__ bias, float* __restrict__ xout, int n){
  int wid  = (blockIdx.x * blockDim.x + threadIdx.x) >> 6;
  int lane = threadIdx.x & 63;
  if (wid >= n) return;
  int hw = lane >> 5;
  int sl = lane & 31;
  const float4* xl4 = reinterpret_cast<const float4*>(xl);
  float4 xrv = reinterpret_cast<const float4*>(xr)[wid*32 + sl];
  constexpr float L2E = 1.44269504f;
  float4 av = reinterpret_cast<const float4*>(att)[sl];
  float a0 = av.x*L2E, a1 = av.y*L2E, a2 = av.z*L2E, a3 = av.w*L2E;
  float m = 0.f, ssum = 0.f;
  float ac0 = 0.f, ac1 = 0.f, ac2 = 0.f, ac3 = 0.f;
  int start = row_ptr[wid], end = row_ptr[wid+1];
  for (int p = start; p < end; p += 2){
    int s0 = srcs[p];                                // uniform -> s_load
    int s1 = (p+1 < end) ? srcs[p+1] : s0;
    int sidx = hw ? s1 : s0;
    bool valid = (p + hw) < end;
    float4 v = xl4[sidx*32 + sl];
    float e = fmaf(a3, leaky(v.w+xrv.w), fmaf(a2, leaky(v.z+xrv.z),
              fmaf(a1, leaky(v.y+xrv.y), a0*leaky(v.x+xrv.x))));
    e += __shfl_xor(e, 1);
    e += __shfl_xor(e, 2);                            // head score in 4 lanes
    if (!valid) e = -INFINITY;
    if (__any(e - m > 8.f)){                          // rare rescale
      float mn = fmaxf(m, e);
      float sc = __builtin_amdgcn_exp2f(m - mn);
      ssum *= sc; ac0 *= sc; ac1 *= sc; ac2 *= sc; ac3 *= sc;
      m = mn;
    }
    float pr = __builtin_amdgcn_exp2f(e - m);         // 0 for invalid lane
    ssum += pr;
    ac0 = fmaf(pr, v.x, ac0);
    ac1 = fmaf(pr, v.y, ac1);
    ac2 = fmaf(pr, v.z, ac2);
    ac3 = fmaf(pr, v.w, ac3);
  }
  // flash-merge the two half-wave partial states (same dims, disjoint edges)
  float mo = __shfl_xor(m, 32);
  float so = __shfl_xor(ssum, 32);
  float b0 = __shfl_xor(ac0, 32), b1 = __shfl_xor(ac1, 32),
        b2 = __shfl_xor(ac2, 32), b3 = __shfl_xor(ac3, 32);
  float mm = fmaxf(m, mo);
  float sca = __builtin_amdgcn_exp2f(m - mm);
  float scb = __builtin_amdgcn_exp2f(mo - mm);
  ssum = ssum*sca + so*scb;
  ac0 = ac0*sca + b0*scb;  ac1 = ac1*sca + b1*scb;
  ac2 = ac2*sca + b2*scb;  ac3 = ac3*sca + b3*scb;
  float o0=0.f, o1=0.f, o2=0.f, o3=0.f;
  if (end > start){
    float inv = 1.f/ssum;
    o0 = ac0*inv; o1 = ac1*inv; o2 = ac2*inv; o3 = ac3*inv;
  }
  float4 bv = reinterpret_cast<const float4*>(bias)[sl];
  float4 outv = make_float4(elu1(o0+bv.x), elu1(o1+bv.y),
                            elu1(o2+bv.z), elu1(o3+bv.w));
  reinterpret_cast<float4*>(xout)[wid*32 + sl] = outv;
}

// ---------------- graph node ranges (batch is sorted) ----------------
__global__ void k_graph_ptr(const int* __restrict__ batch, int* __restrict__ gp,
                            int n, int nb){
  int b = blockIdx.x*blockDim.x + threadIdx.x;
  if (b > nb) return;
  int lo = 0, hi = n;
  while (lo < hi){ int mid = (lo+hi)>>1; if (batch[mid] < b) lo = mid+1; else hi = mid; }
  gp[b] = lo;   // for b==nb this yields n
}

// ---------------- gated sum-pool + max-pool: one wave per graph ----------------
__global__ __launch_bounds__(256) void k_pool(const float* __restrict__ x,
    const int* __restrict__ gp, const float* __restrict__ read_w,
    const float* __restrict__ read_b, float* __restrict__ mol, int nb){
  int w    = (blockIdx.x * blockDim.x + threadIdx.x) >> 6;
  int lane = threadIdx.x & 63;
  if (w >= nb) return;
  const float2* x2 = reinterpret_cast<const float2*>(x);
  float rw0 = read_w[2*lane], rw1 = read_w[2*lane+1];
  float rb = read_b[0];
  float s0=0.f, s1=0.f, m0=-INFINITY, m1=-INFINITY;
  int start = gp[w], end = gp[w+1];
  for (int nidx = start; nidx < end; ++nidx){
    float2 v = x2[nidx*64 + lane];
    float d = v.x*rw0 + v.y*rw1;
    d += __shfl_xor(d, 1);  d += __shfl_xor(d, 2);  d += __shfl_xor(d, 4);
    d += __shfl_xor(d, 8);  d += __shfl_xor(d, 16); d += __shfl_xor(d, 32);
    float gate = 1.f/(1.f + expf(-(d + rb)));
    s0 += gate*v.x;  s1 += gate*v.y;
    m0 = fmaxf(m0, v.x);  m1 = fmaxf(m1, v.y);
  }
  if (end <= start){ m0 = 0.f; m1 = 0.f; }   // empty graph: isfinite guard
  mol[w*256 + 2*lane]       = s0;
  mol[w*256 + 2*lane+1]     = s1;
  mol[w*256 + 128 + 2*lane]   = m0;
  mol[w*256 + 128 + 2*lane+1] = m1;
}

// ---------------- Boltzmann + MLP head: one block (128 thr) per graph ----------------
__global__ __launch_bounds__(128) void k_head(const float* __restrict__ mol,
    const float* __restrict__ temps, const float* __restrict__ en_w,
    const float* __restrict__ en_b, const float* __restrict__ w1,
    const float* __restrict__ b1, const float* __restrict__ w2,
    const float* __restrict__ b2, float* __restrict__ out, int nb){
  __shared__ float molS[256];
  __shared__ float red[128];
  __shared__ float distS[128];
  __shared__ float hS[64];
  int b = blockIdx.x, tid = threadIdx.x;
  if (b >= nb) return;
  molS[tid]       = mol[b*256 + tid];
  molS[tid + 128] = mol[b*256 + 128 + tid];
  __syncthreads();
  float z = -INFINITY;
  if (tid < K){
    float acc = en_b[tid];
    for (int j=0;j<256;j++) acc += molS[j]*en_w[j*K + tid];
    z = -acc / temps[b];
  }
  red[tid] = z; __syncthreads();
  for (int off=64; off>0; off>>=1){
    if (tid < off) red[tid] = fmaxf(red[tid], red[tid+off]);
    __syncthreads();
  }
  float mx = red[0]; __syncthreads();
  float ex = (tid < K) ? expf(z - mx) : 0.f;
  red[tid] = ex; __syncthreads();
  for (int off=64; off>0; off>>=1){
    if (tid < off) red[tid] += red[tid+off];
    __syncthreads();
  }
  float denom = red[0];
  distS[tid] = ex / denom;
  __syncthreads();
  if (tid < 64){
    float acc = b1[tid];
    for (int k=0;k<K;k++) acc += distS[k]*w1[k*64 + tid];
    hS[tid] = elu1(acc);
  }
  __syncthreads();
  red[tid] = (tid < 64) ? hS[tid]*w2[tid] : 0.f;
  __syncthreads();
  for (int off=32; off>0; off>>=1){
    if (tid < off) red[tid] += red[tid+off];
    __syncthreads();
  }
  if (tid == 0) out[b] = red[0] + b2[0];
}

// ---------------- launch ----------------
extern "C" void kernel_launch(void* const* d_in, const int* in_sizes, int n_in,
                              void* d_out, int out_size, void* d_ws, size_t ws_size,
                              hipStream_t stream){
  const float* x0    = (const float*)d_in[0];
  const int*   ei    = (const int*)  d_in[1];
  const int*   batch = (const int*)  d_in[2];
  const float* temps = (const float*)d_in[3];
  const float* wl    = (const float*)d_in[4];
  const float* wr    = (const float*)d_in[5];
  const float* att   = (const float*)d_in[6];
  const float* gatb  = (const float*)d_in[7];
  const float* read_w= (const float*)d_in[8];
  const float* read_b= (const float*)d_in[9];
  const float* en_w  = (const float*)d_in[10];
  const float* en_b  = (const float*)d_in[11];
  const float* w1    = (const float*)d_in[12];
  const float* b1    = (const float*)d_in[13];
  const float* w2    = (const float*)d_in[14];
  const float* b2    = (const float*)d_in[15];
  float* out = (float*)d_out;

  const int N = in_sizes[0] / HID;
  const int E = in_sizes[1] / 2;
  const int B = in_sizes[3];
  const int* src = ei;
  const int* dst = ei + E;

  char* ws = (char*)d_ws;
  size_t off = 0;
  auto alloc = [&](size_t bytes)->char*{
    char* p = ws + off; off += (bytes + 255) & ~size_t(255); return p;
  };
  float* xl    = (float*)alloc(sizeof(float)*(size_t)N*HID);
  float* xr    = (float*)alloc(sizeof(float)*(size_t)N*HID);
  float* xb    = (float*)alloc(sizeof(float)*(size_t)N*HID);
  float* mol   = (float*)alloc(sizeof(float)*(size_t)B*2*HID);
  int* row_ptr = (int*)alloc(sizeof(int)*(size_t)(N+1));
  int* deg     = (int*)alloc(sizeof(int)*(size_t)N);
  int* fill    = (int*)alloc(sizeof(int)*(size_t)N);
  int* srcs    = (int*)alloc(sizeof(int)*(size_t)E);
  int* bsum    = (int*)alloc(sizeof(int)*1024);
  int* gp      = (int*)alloc(sizeof(int)*(size_t)(B+1));

  // --- CSR by dst (once per call; reused by all 4 layers) ---
  int nchunk = (N + 1023) / 1024;
  k_zero<<<(N+255)/256, 256, 0, stream>>>(deg, N);
  k_zero<<<(N+255)/256, 256, 0, stream>>>(fill, N);
  k_deg<<<(E+255)/256, 256, 0, stream>>>(dst, deg, E);
  k_scan1<<<nchunk, 256, 0, stream>>>(deg, row_ptr, bsum, N);
  k_scan2<<<1, 1, 0, stream>>>(bsum, nchunk);
  k_scan3<<<(N+255)/256, 256, 0, stream>>>(row_ptr, bsum, N);
  k_scatter<<<(E+255)/256, 256, 0, stream>>>(src, dst, row_ptr, fill, srcs, E);

  // --- 4 GATv2 layers ---
  const float* xin = x0;
  for (int l = 0; l < LAY; ++l){
    dim3 ggrid((N + 127)/128, 2);
    k_gemm2<<<ggrid, 256, 0, stream>>>(xin, wl + (size_t)l*HID*HID,
                                       wr + (size_t)l*HID*HID, xl, xr, N);
    k_gat<<<(N+3)/4, 256, 0, stream>>>(xl, xr, row_ptr, srcs,
                                       att + (size_t)l*H*DH, gatb + (size_t)l*HID, xb, N);
    xin = xb;
  }

  // --- readout + head ---
  k_graph_ptr<<<(B+1+255)/256, 256, 0, stream>>>(batch, gp, N, B);
  k_pool<<<(B+3)/4, 256, 0, stream>>>(xb, gp, read_w, read_b, mol, B);
  k_head<<<B, 128, 0, stream>>>(mol, temps, en_w, en_b, w1, b1, w2, b2, out, B);
}

// Round 4
// 1258.328 us; speedup vs baseline: 1.3591x; 1.0959x over previous
//
#include <hip/hip_runtime.h>
#include <math.h>

// Model constants (shapes from reference)
static constexpr int HID = 128;
static constexpr int H   = 8;
static constexpr int DH  = 16;
static constexpr int LAY = 4;
static constexpr int K   = 100;

__device__ __forceinline__ float leaky(float x){ return fmaxf(x, 0.2f*x); }
__device__ __forceinline__ float elu1(float x){ return x > 0.f ? x : expm1f(x); }

// ---------------- utility ----------------
__global__ void k_zero(int* p, int n){
  int i = blockIdx.x*blockDim.x + threadIdx.x;
  if (i < n) p[i] = 0;
}

// ---------------- CSR build (counting sort by dst) ----------------
__global__ void k_deg(const int* __restrict__ dst, int* __restrict__ deg, int E){
  int e = blockIdx.x*blockDim.x + threadIdx.x;
  if (e < E) atomicAdd(&deg[dst[e]], 1);
}

// chunked scan: 1024 elems/block, 256 threads x 4
__global__ void k_scan1(const int* __restrict__ deg, int* __restrict__ row_ptr,
                        int* __restrict__ bsum, int n){
  __shared__ int s[256];
  int tid = threadIdx.x;
  int base = blockIdx.x*1024 + tid*4;
  int v0 = (base+0 < n) ? deg[base+0] : 0;
  int v1 = (base+1 < n) ? deg[base+1] : 0;
  int v2 = (base+2 < n) ? deg[base+2] : 0;
  int v3 = (base+3 < n) ? deg[base+3] : 0;
  int t1 = v0+v1, t2 = t1+v2, t3 = t2+v3;
  s[tid] = t3;
  __syncthreads();
  for (int off=1; off<256; off<<=1){
    int t = (tid >= off) ? s[tid-off] : 0;
    __syncthreads();
    s[tid] += t;
    __syncthreads();
  }
  int excl = tid ? s[tid-1] : 0;
  if (base+0 < n) row_ptr[1+base+0] = excl + v0;
  if (base+1 < n) row_ptr[1+base+1] = excl + t1;
  if (base+2 < n) row_ptr[1+base+2] = excl + t2;
  if (base+3 < n) row_ptr[1+base+3] = excl + t3;
  if (tid == 255) bsum[blockIdx.x] = s[255];
}

__global__ void k_scan2(int* bsum, int nb){
  if (threadIdx.x == 0 && blockIdx.x == 0){
    int run = 0;
    for (int i=0;i<nb;i++){ int t = bsum[i]; bsum[i] = run; run += t; }
  }
}

__global__ void k_scan3(int* row_ptr, const int* __restrict__ bsum, int n){
  int i = blockIdx.x*blockDim.x + threadIdx.x;
  if (i < n) row_ptr[1+i] += bsum[i >> 10];
  if (i == 0) row_ptr[0] = 0;
}

__global__ void k_scatter(const int* __restrict__ src, const int* __restrict__ dst,
                          const int* __restrict__ row_ptr, int* __restrict__ fill,
                          int* __restrict__ srcs, int E){
  int e = blockIdx.x*blockDim.x + threadIdx.x;
  if (e < E){
    int d = dst[e];
    int pos = row_ptr[d] + atomicAdd(&fill[d], 1);
    srcs[pos] = src[e];
  }
}

// ---------------- fused xl/xr GEMM: [N,128] @ [128,128] x2 ----------------
// Register-tiled: block = 256 threads (tx 0..15, ty 0..15) computes
// 128 rows x 64 cols for BOTH wl and wr (x read shared -> free 2x reuse).
// Per thread: 8 rows x 4 cols x 2 mats = 64 accumulators. k4 loop manually
// unrolled x2: 16 w-loads batched, then 512 FMA -> w-load latency amortized.
__global__ __launch_bounds__(256) void k_gemm2(const float* __restrict__ x,
    const float* __restrict__ wl, const float* __restrict__ wr,
    float* __restrict__ xl, float* __restrict__ xr, int nrows){
  __shared__ float4 xs[128][16];
  const int tid = threadIdx.x;
  const int tx = tid & 15, ty = tid >> 4;
  const int r0 = blockIdx.x * 128;
  const int c0 = blockIdx.y * 64 + tx * 4;
  const float4* x4 = reinterpret_cast<const float4*>(x);
  float4 accL[8], accR[8];           // [row i] -> 4 cols
  #pragma unroll
  for (int i=0;i<8;i++){
    accL[i] = make_float4(0.f,0.f,0.f,0.f);
    accR[i] = make_float4(0.f,0.f,0.f,0.f);
  }
  const int swz = ty & 3;
  for (int kk = 0; kk < 128; kk += 64){
    if (kk) __syncthreads();
    #pragma unroll
    for (int it = 0; it < 8; ++it){
      int idx = tid + it*256;
      int r = idx >> 4, k4 = idx & 15;
      float4 v = make_float4(0.f,0.f,0.f,0.f);
      if (r0 + r < nrows) v = x4[(size_t)(r0+r)*32 + (kk>>2) + k4];
      xs[r][k4 ^ ((r>>3)&3)] = v;
    }
    __syncthreads();
    for (int k4 = 0; k4 < 16; k4 += 2){
      const float* wlp = wl + (size_t)(kk + 4*k4)*128 + c0;
      const float* wrp = wr + (size_t)(kk + 4*k4)*128 + c0;
      float4 al0 = *reinterpret_cast<const float4*>(wlp);
      float4 al1 = *reinterpret_cast<const float4*>(wlp + 128);
      float4 al2 = *reinterpret_cast<const float4*>(wlp + 256);
      float4 al3 = *reinterpret_cast<const float4*>(wlp + 384);
      float4 ar0 = *reinterpret_cast<const float4*>(wrp);
      float4 ar1 = *reinterpret_cast<const float4*>(wrp + 128);
      float4 ar2 = *reinterpret_cast<const float4*>(wrp + 256);
      float4 ar3 = *reinterpret_cast<const float4*>(wrp + 384);
      float4 bl0 = *reinterpret_cast<const float4*>(wlp + 512);
      float4 bl1 = *reinterpret_cast<const float4*>(wlp + 640);
      float4 bl2 = *reinterpret_cast<const float4*>(wlp + 768);
      float4 bl3 = *reinterpret_cast<const float4*>(wlp + 896);
      float4 br0 = *reinterpret_cast<const float4*>(wrp + 512);
      float4 br1 = *reinterpret_cast<const float4*>(wrp + 640);
      float4 br2 = *reinterpret_cast<const float4*>(wrp + 768);
      float4 br3 = *reinterpret_cast<const float4*>(wrp + 896);
      const int kca = k4 ^ swz;
      const int kcb = (k4+1) ^ swz;
      #pragma unroll
      for (int i = 0; i < 8; ++i){
        float4 xv = xs[ty*8 + i][kca];
        accL[i].x = fmaf(xv.w, al3.x, fmaf(xv.z, al2.x, fmaf(xv.y, al1.x, fmaf(xv.x, al0.x, accL[i].x))));
        accL[i].y = fmaf(xv.w, al3.y, fmaf(xv.z, al2.y, fmaf(xv.y, al1.y, fmaf(xv.x, al0.y, accL[i].y))));
        accL[i].z = fmaf(xv.w, al3.z, fmaf(xv.z, al2.z, fmaf(xv.y, al1.z, fmaf(xv.x, al0.z, accL[i].z))));
        accL[i].w = fmaf(xv.w, al3.w, fmaf(xv.z, al2.w, fmaf(xv.y, al1.w, fmaf(xv.x, al0.w, accL[i].w))));
        accR[i].x = fmaf(xv.w, ar3.x, fmaf(xv.z, ar2.x, fmaf(xv.y, ar1.x, fmaf(xv.x, ar0.x, accR[i].x))));
        accR[i].y = fmaf(xv.w, ar3.y, fmaf(xv.z, ar2.y, fmaf(xv.y, ar1.y, fmaf(xv.x, ar0.y, accR[i].y))));
        accR[i].z = fmaf(xv.w, ar3.z, fmaf(xv.z, ar2.z, fmaf(xv.y, ar1.z, fmaf(xv.x, ar0.z, accR[i].z))));
        accR[i].w = fmaf(xv.w, ar3.w, fmaf(xv.z, ar2.w, fmaf(xv.y, ar1.w, fmaf(xv.x, ar0.w, accR[i].w))));
      }
      #pragma unroll
      for (int i = 0; i < 8; ++i){
        float4 xv = xs[ty*8 + i][kcb];
        accL[i].x = fmaf(xv.w, bl3.x, fmaf(xv.z, bl2.x, fmaf(xv.y, bl1.x, fmaf(xv.x, bl0.x, accL[i].x))));
        accL[i].y = fmaf(xv.w, bl3.y, fmaf(xv.z, bl2.y, fmaf(xv.y, bl1.y, fmaf(xv.x, bl0.y, accL[i].y))));
        accL[i].z = fmaf(xv.w, bl3.z, fmaf(xv.z, bl2.z, fmaf(xv.y, bl1.z, fmaf(xv.x, bl0.z, accL[i].z))));
        accL[i].w = fmaf(xv.w, bl3.w, fmaf(xv.z, bl2.w, fmaf(xv.y, bl1.w, fmaf(xv.x, bl0.w, accL[i].w))));
        accR[i].x = fmaf(xv.w, br3.x, fmaf(xv.z, br2.x, fmaf(xv.y, br1.x, fmaf(xv.x, br0.x, accR[i].x))));
        accR[i].y = fmaf(xv.w, br3.y, fmaf(xv.z, br2.y, fmaf(xv.y, br1.y, fmaf(xv.x, br0.y, accR[i].y))));
        accR[i].z = fmaf(xv.w, br3.z, fmaf(xv.z, br2.z, fmaf(xv.y, br1.z, fmaf(xv.x, br0.z, accR[i].z))));
        accR[i].w = fmaf(xv.w, br3.w, fmaf(xv.z, br2.w, fmaf(xv.y, br1.w, fmaf(xv.x, br0.w, accR[i].w))));
      }
    }
  }
  #pragma unroll
  for (int i = 0; i < 8; ++i){
    int row = r0 + ty*8 + i;
    if (row < nrows){
      *reinterpret_cast<float4*>(&xl[(size_t)row*128 + c0]) = accL[i];
      *reinterpret_cast<float4*>(&xr[(size_t)row*128 + c0]) = accR[i];
    }
  }
}

// ---------------- GATv2 edge pass: one wave per dst node, 4 edges/iter ----
// Edge slot egrp = lane>>4 (4 edges in flight); lane ql = lane&15 owns dims
// 8ql..8ql+7 (2 float4 gathers). Head h = ql>>1 spans 2 lanes -> 1 shfl_xor.
// Edge indices come from ONE coalesced load of 64 per chunk, distributed via
// __shfl (no dependent s_load chain). Next iteration's 2 gathers prefetched
// before current compute (1-deep pipeline). Softmax in log2 domain with
// defer-max (THR=8); flash-merge of 4 edge-slot states at the end.
__global__ __launch_bounds__(256) void k_gat(const float* __restrict__ xl,
    const float* __restrict__ xr, const int* __restrict__ row_ptr,
    const int* __restrict__ srcs, const float* __restrict__ att,
    const float* __restrict__ bias, float* __restrict__ xout, int n){
  int wid  = (blockIdx.x * blockDim.x + threadIdx.x) >> 6;
  int lane = threadIdx.x & 63;
  if (wid >= n) return;
  const int egrp = lane >> 4;
  const int ql   = lane & 15;
  const float4* xl4 = reinterpret_cast<const float4*>(xl);
  float4 xr0 = reinterpret_cast<const float4*>(xr)[wid*32 + (ql<<1)];
  float4 xr1 = reinterpret_cast<const float4*>(xr)[wid*32 + (ql<<1) + 1];
  constexpr float L2E = 1.44269504f;
  float4 aw0 = reinterpret_cast<const float4*>(att)[(ql<<1)];
  float4 aw1 = reinterpret_cast<const float4*>(att)[(ql<<1) + 1];
  const float a0 = aw0.x*L2E, a1 = aw0.y*L2E, a2 = aw0.z*L2E, a3 = aw0.w*L2E;
  const float a4 = aw1.x*L2E, a5 = aw1.y*L2E, a6 = aw1.z*L2E, a7 = aw1.w*L2E;
  float m = 0.f, ssum = 0.f;
  float ac0=0.f, ac1=0.f, ac2=0.f, ac3=0.f, ac4=0.f, ac5=0.f, ac6=0.f, ac7=0.f;
  const int start = row_ptr[wid], end = row_ptr[wid+1];
  for (int base = start; base < end; base += 64){
    int cnt = end - base; if (cnt > 64) cnt = 64;
    int sv = (lane < cnt) ? srcs[base + lane] : 0;
    int iters = (cnt + 3) >> 2;
    int sidx = __shfl(sv, egrp);
    float4 v0 = xl4[(size_t)sidx*32 + (ql<<1)];
    float4 v1 = xl4[(size_t)sidx*32 + (ql<<1) + 1];
    for (int t = 0; t < iters; ++t){
      float4 c0 = v0, c1 = v1;
      bool valid = ((t<<2) + egrp) < cnt;
      if (t + 1 < iters){
        int sj = __shfl(sv, ((t+1)<<2) + egrp);
        v0 = xl4[(size_t)sj*32 + (ql<<1)];
        v1 = xl4[(size_t)sj*32 + (ql<<1) + 1];
      }
      float e =       a0 * leaky(c0.x + xr0.x);
      e = fmaf(a1, leaky(c0.y + xr0.y), e);
      e = fmaf(a2, leaky(c0.z + xr0.z), e);
      e = fmaf(a3, leaky(c0.w + xr0.w), e);
      e = fmaf(a4, leaky(c1.x + xr1.x), e);
      e = fmaf(a5, leaky(c1.y + xr1.y), e);
      e = fmaf(a6, leaky(c1.z + xr1.z), e);
      e = fmaf(a7, leaky(c1.w + xr1.w), e);
      e += __shfl_xor(e, 1);                 // full head score in both lanes
      if (!valid) e = -INFINITY;
      if (__any(e - m > 8.f)){               // rare rescale
        float mn = fmaxf(m, e);
        float sc = __builtin_amdgcn_exp2f(m - mn);
        ssum *= sc;
        ac0 *= sc; ac1 *= sc; ac2 *= sc; ac3 *= sc;
        ac4 *= sc; ac5 *= sc; ac6 *= sc; ac7 *= sc;
        m = mn;
      }
      float pr = __builtin_amdgcn_exp2f(e - m);   // 0 for invalid (e=-inf)
      ssum += pr;
      ac0 = fmaf(pr, c0.x, ac0);  ac1 = fmaf(pr, c0.y, ac1);
      ac2 = fmaf(pr, c0.z, ac2);  ac3 = fmaf(pr, c0.w, ac3);
      ac4 = fmaf(pr, c1.x, ac4);  ac5 = fmaf(pr, c1.y, ac5);
      ac6 = fmaf(pr, c1.z, ac6);  ac7 = fmaf(pr, c1.w, ac7);
    }
  }
  // flash-merge the 4 edge-slot partial states (same dims, disjoint edges)
  #pragma unroll
  for (int w = 16; w <= 32; w <<= 1){
    float mo = __shfl_xor(m, w);
    float so = __shfl_xor(ssum, w);
    float b0 = __shfl_xor(ac0, w), b1 = __shfl_xor(ac1, w);
    float b2 = __shfl_xor(ac2, w), b3 = __shfl_xor(ac3, w);
    float b4 = __shfl_xor(ac4, w), b5 = __shfl_xor(ac5, w);
    float b6 = __shfl_xor(ac6, w), b7 = __shfl_xor(ac7, w);
    float mm = fmaxf(m, mo);
    float sa = __builtin_amdgcn_exp2f(m - mm);
    float sb = __builtin_amdgcn_exp2f(mo - mm);
    ssum = ssum*sa + so*sb;
    ac0 = ac0*sa + b0*sb;  ac1 = ac1*sa + b1*sb;
    ac2 = ac2*sa + b2*sb;  ac3 = ac3*sa + b3*sb;
    ac4 = ac4*sa + b4*sb;  ac5 = ac5*sa + b5*sb;
    ac6 = ac6*sa + b6*sb;  ac7 = ac7*sa + b7*sb;
    m = mm;
  }
  float inv = (end > start) ? 1.f/ssum : 0.f;
  const float4* b4p = reinterpret_cast<const float4*>(bias);
  if (egrp == 0){
    float4 bv = b4p[(ql<<1)];
    float4 o = make_float4(elu1(fmaf(ac0, inv, bv.x)), elu1(fmaf(ac1, inv, bv.y)),
                           elu1(fmaf(ac2, inv, bv.z)), elu1(fmaf(ac3, inv, bv.w)));
    reinterpret_cast<float4*>(xout)[wid*32 + (ql<<1)] = o;
  } else if (egrp == 1){
    float4 bv = b4p[(ql<<1) + 1];
    float4 o = make_float4(elu1(fmaf(ac4, inv, bv.x)), elu1(fmaf(ac5, inv, bv.y)),
                           elu1(fmaf(ac6, inv, bv.z)), elu1(fmaf(ac7, inv, bv.w)));
    reinterpret_cast<float4*>(xout)[wid*32 + (ql<<1) + 1] = o;
  }
}

// ---------------- graph node ranges (batch is sorted) ----------------
__global__ void k_graph_ptr(const int* __restrict__ batch, int* __restrict__ gp,
                            int n, int nb){
  int b = blockIdx.x*blockDim.x + threadIdx.x;
  if (b > nb) return;
  int lo = 0, hi = n;
  while (lo < hi){ int mid = (lo+hi)>>1; if (batch[mid] < b) lo = mid+1; else hi = mid; }
  gp[b] = lo;   // for b==nb this yields n
}

// ---------------- gated sum-pool + max-pool: one wave per graph ----------------
__global__ __launch_bounds__(256) void k_pool(const float* __restrict__ x,
    const int* __restrict__ gp, const float* __restrict__ read_w,
    const float* __restrict__ read_b, float* __restrict__ mol, int nb){
  int w    = (blockIdx.x * blockDim.x + threadIdx.x) >> 6;
  int lane = threadIdx.x & 63;
  if (w >= nb) return;
  const float2* x2 = reinterpret_cast<const float2*>(x);
  float rw0 = read_w[2*lane], rw1 = read_w[2*lane+1];
  float rb = read_b[0];
  float s0=0.f, s1=0.f, m0=-INFINITY, m1=-INFINITY;
  int start = gp[w], end = gp[w+1];
  for (int nidx = start; nidx < end; ++nidx){
    float2 v = x2[nidx*64 + lane];
    float d = v.x*rw0 + v.y*rw1;
    d += __shfl_xor(d, 1);  d += __shfl_xor(d, 2);  d += __shfl_xor(d, 4);
    d += __shfl_xor(d, 8);  d += __shfl_xor(d, 16); d += __shfl_xor(d, 32);
    float gate = 1.f/(1.f + expf(-(d + rb)));
    s0 += gate*v.x;  s1 += gate*v.y;
    m0 = fmaxf(m0, v.x);  m1 = fmaxf(m1, v.y);
  }
  if (end <= start){ m0 = 0.f; m1 = 0.f; }   // empty graph: isfinite guard
  mol[w*256 + 2*lane]       = s0;
  mol[w*256 + 2*lane+1]     = s1;
  mol[w*256 + 128 + 2*lane]   = m0;
  mol[w*256 + 128 + 2*lane+1] = m1;
}

// ---------------- Boltzmann + MLP head: one block (128 thr) per graph ----------------
__global__ __launch_bounds__(128) void k_head(const float* __restrict__ mol,
    const float* __restrict__ temps, const float* __restrict__ en_w,
    const float* __restrict__ en_b, const float* __restrict__ w1,
    const float* __restrict__ b1, const float* __restrict__ w2,
    const float* __restrict__ b2, float* __restrict__ out, int nb){
  __shared__ float molS[256];
  __shared__ float red[128];
  __shared__ float distS[128];
  __shared__ float hS[64];
  int b = blockIdx.x, tid = threadIdx.x;
  if (b >= nb) return;
  molS[tid]       = mol[b*256 + tid];
  molS[tid + 128] = mol[b*256 + 128 + tid];
  __syncthreads();
  float z = -INFINITY;
  if (tid < K){
    float acc = en_b[tid];
    for (int j=0;j<256;j++) acc += molS[j]*en_w[j*K + tid];
    z = -acc / temps[b];
  }
  red[tid] = z; __syncthreads();
  for (int off=64; off>0; off>>=1){
    if (tid < off) red[tid] = fmaxf(red[tid], red[tid+off]);
    __syncthreads();
  }
  float mx = red[0]; __syncthreads();
  float ex = (tid < K) ? expf(z - mx) : 0.f;
  red[tid] = ex; __syncthreads();
  for (int off=64; off>0; off>>=1){
    if (tid < off) red[tid] += red[tid+off];
    __syncthreads();
  }
  float denom = red[0];
  distS[tid] = ex / denom;
  __syncthreads();
  if (tid < 64){
    float acc = b1[tid];
    for (int k=0;k<K;k++) acc += distS[k]*w1[k*64 + tid];
    hS[tid] = elu1(acc);
  }
  __syncthreads();
  red[tid] = (tid < 64) ? hS[tid]*w2[tid] : 0.f;
  __syncthreads();
  for (int off=32; off>0; off>>=1){
    if (tid < off) red[tid] += red[tid+off];
    __syncthreads();
  }
  if (tid == 0) out[b] = red[0] + b2[0];
}

// ---------------- launch ----------------
extern "C" void kernel_launch(void* const* d_in, const int* in_sizes, int n_in,
                              void* d_out, int out_size, void* d_ws, size_t ws_size,
                              hipStream_t stream){
  const float* x0    = (const float*)d_in[0];
  const int*   ei    = (const int*)  d_in[1];
  const int*   batch = (const int*)  d_in[2];
  const float* temps = (const float*)d_in[3];
  const float* wl    = (const float*)d_in[4];
  const float* wr    = (const float*)d_in[5];
  const float* att   = (const float*)d_in[6];
  const float* gatb  = (const float*)d_in[7];
  const float* read_w= (const float*)d_in[8];
  const float* read_b= (const float*)d_in[9];
  const float* en_w  = (const float*)d_in[10];
  const float* en_b  = (const float*)d_in[11];
  const float* w1    = (const float*)d_in[12];
  const float* b1    = (const float*)d_in[13];
  const float* w2    = (const float*)d_in[14];
  const float* b2    = (const float*)d_in[15];
  float* out = (float*)d_out;

  const int N = in_sizes[0] / HID;
  const int E = in_sizes[1] / 2;
  const int B = in_sizes[3];
  const int* src = ei;
  const int* dst = ei + E;

  char* ws = (char*)d_ws;
  size_t off = 0;
  auto alloc = [&](size_t bytes)->char*{
    char* p = ws + off; off += (bytes + 255) & ~size_t(255); return p;
  };
  float* xl    = (float*)alloc(sizeof(float)*(size_t)N*HID);
  float* xr    = (float*)alloc(sizeof(float)*(size_t)N*HID);
  float* xb    = (float*)alloc(sizeof(float)*(size_t)N*HID);
  float* mol   = (float*)alloc(sizeof(float)*(size_t)B*2*HID);
  int* row_ptr = (int*)alloc(sizeof(int)*(size_t)(N+1));
  int* deg     = (int*)alloc(sizeof(int)*(size_t)N);
  int* fill    = (int*)alloc(sizeof(int)*(size_t)N);
  int* srcs    = (int*)alloc(sizeof(int)*(size_t)E);
  int* bsum    = (int*)alloc(sizeof(int)*1024);
  int* gp      = (int*)alloc(sizeof(int)*(size_t)(B+1));

  // --- CSR by dst (once per call; reused by all 4 layers) ---
  int nchunk = (N + 1023) / 1024;
  k_zero<<<(N+255)/256, 256, 0, stream>>>(deg, N);
  k_zero<<<(N+255)/256, 256, 0, stream>>>(fill, N);
  k_deg<<<(E+255)/256, 256, 0, stream>>>(dst, deg, E);
  k_scan1<<<nchunk, 256, 0, stream>>>(deg, row_ptr, bsum, N);
  k_scan2<<<1, 1, 0, stream>>>(bsum, nchunk);
  k_scan3<<<(N+255)/256, 256, 0, stream>>>(row_ptr, bsum, N);
  k_scatter<<<(E+255)/256, 256, 0, stream>>>(src, dst, row_ptr, fill, srcs, E);

  // --- 4 GATv2 layers ---
  const float* xin = x0;
  for (int l = 0; l < LAY; ++l){
    dim3 ggrid((N + 127)/128, 2);
    k_gemm2<<<ggrid, 256, 0, stream>>>(xin, wl + (size_t)l*HID*HID,
                                       wr + (size_t)l*HID*HID, xl, xr, N);
    k_gat<<<(N+3)/4, 256, 0, stream>>>(xl, xr, row_ptr, srcs,
                                       att + (size_t)l*H*DH, gatb + (size_t)l*HID, xb, N);
    xin = xb;
  }

  // --- readout + head ---
  k_graph_ptr<<<(B+1+255)/256, 256, 0, stream>>>(batch, gp, N, B);
  k_pool<<<(B+3)/4, 256, 0, stream>>>(xb, gp, read_w, read_b, mol, B);
  k_head<<<B, 128, 0, stream>>>(mol, temps, en_w, en_b, w1, b1, w2, b2, out, B);
}

// Round 5
// 1240.957 us; speedup vs baseline: 1.3782x; 1.0140x over previous
//
#include <hip/hip_runtime.h>
#include <math.h>

// Model constants (shapes from reference)
static constexpr int HID = 128;
static constexpr int H   = 8;
static constexpr int DH  = 16;
static constexpr int LAY = 4;
static constexpr int K   = 100;

__device__ __forceinline__ float leaky(float x){ return fmaxf(x, 0.2f*x); }
__device__ __forceinline__ float elu1(float x){ return x > 0.f ? x : expm1f(x); }

// ---------------- utility ----------------
__global__ void k_zero2(int* p, int* q, int n){
  int i = blockIdx.x*blockDim.x + threadIdx.x;
  if (i < n){ p[i] = 0; q[i] = 0; }
}

// ---------------- CSR build (counting sort by dst) ----------------
__global__ void k_deg(const int* __restrict__ dst, int* __restrict__ deg, int E){
  int e = blockIdx.x*blockDim.x + threadIdx.x;
  if (e < E) atomicAdd(&deg[dst[e]], 1);
}

// chunked scan: 1024 elems/block, 256 threads x 4
__global__ void k_scan1(const int* __restrict__ deg, int* __restrict__ row_ptr,
                        int* __restrict__ bsum, int n){
  __shared__ int s[256];
  int tid = threadIdx.x;
  int base = blockIdx.x*1024 + tid*4;
  int v0 = (base+0 < n) ? deg[base+0] : 0;
  int v1 = (base+1 < n) ? deg[base+1] : 0;
  int v2 = (base+2 < n) ? deg[base+2] : 0;
  int v3 = (base+3 < n) ? deg[base+3] : 0;
  int t1 = v0+v1, t2 = t1+v2, t3 = t2+v3;
  s[tid] = t3;
  __syncthreads();
  for (int off=1; off<256; off<<=1){
    int t = (tid >= off) ? s[tid-off] : 0;
    __syncthreads();
    s[tid] += t;
    __syncthreads();
  }
  int excl = tid ? s[tid-1] : 0;
  if (base+0 < n) row_ptr[1+base+0] = excl + v0;
  if (base+1 < n) row_ptr[1+base+1] = excl + t1;
  if (base+2 < n) row_ptr[1+base+2] = excl + t2;
  if (base+3 < n) row_ptr[1+base+3] = excl + t3;
  if (tid == 255) bsum[blockIdx.x] = s[255];
}

__global__ void k_scan2(int* bsum, int nb){
  if (threadIdx.x == 0 && blockIdx.x == 0){
    int run = 0;
    for (int i=0;i<nb;i++){ int t = bsum[i]; bsum[i] = run; run += t; }
  }
}

__global__ void k_scan3(int* row_ptr, const int* __restrict__ bsum, int n){
  int i = blockIdx.x*blockDim.x + threadIdx.x;
  if (i < n) row_ptr[1+i] += bsum[i >> 10];
  if (i == 0) row_ptr[0] = 0;
}

__global__ void k_scatter(const int* __restrict__ src, const int* __restrict__ dst,
                          const int* __restrict__ row_ptr, int* __restrict__ fill,
                          int* __restrict__ srcs, int E){
  int e = blockIdx.x*blockDim.x + threadIdx.x;
  if (e < E){
    int d = dst[e];
    int pos = row_ptr[d] + atomicAdd(&fill[d], 1);
    srcs[pos] = src[e];
  }
}

// ---------------- fused xl/xr GEMM: [N,128] @ [128,128] x2 ----------------
// Register-tiled 128x64 (x2 mats) per block, 8r x 4c x 2m = 64 acc/thread.
// Ping-pong w-register prefetch: while the FMA block for k4 (set A, 256
// FMA-instr = 512 cyc/wave) executes, the 16 dwordx4 loads for k4+1 (set B)
// are in flight -> load-use distance = one FMA block > L2 latency, so a
// single wave hides w latency regardless of occupancy. VGPR ~150 -> ~3
// waves/SIMD, which is enough since latency is pipelined within the wave.
#define LOADW(S, j) do {                                                      \
    const float* lp = wlp + (size_t)(j)*512;                                  \
    const float* rp = wrp + (size_t)(j)*512;                                  \
    S##l0 = *reinterpret_cast<const float4*>(lp);                             \
    S##l1 = *reinterpret_cast<const float4*>(lp + 128);                       \
    S##l2 = *reinterpret_cast<const float4*>(lp + 256);                       \
    S##l3 = *reinterpret_cast<const float4*>(lp + 384);                       \
    S##r0 = *reinterpret_cast<const float4*>(rp);                             \
    S##r1 = *reinterpret_cast<const float4*>(rp + 128);                       \
    S##r2 = *reinterpret_cast<const float4*>(rp + 256);                       \
    S##r3 = *reinterpret_cast<const float4*>(rp + 384);                       \
  } while(0)

#define FMABLK(S, kc) do {                                                    \
    _Pragma("unroll")                                                         \
    for (int i = 0; i < 8; ++i){                                              \
      float4 xv = xs[ty*8 + i][kc];                                           \
      accL[i].x = fmaf(xv.w, S##l3.x, fmaf(xv.z, S##l2.x, fmaf(xv.y, S##l1.x, fmaf(xv.x, S##l0.x, accL[i].x)))); \
      accL[i].y = fmaf(xv.w, S##l3.y, fmaf(xv.z, S##l2.y, fmaf(xv.y, S##l1.y, fmaf(xv.x, S##l0.y, accL[i].y)))); \
      accL[i].z = fmaf(xv.w, S##l3.z, fmaf(xv.z, S##l2.z, fmaf(xv.y, S##l1.z, fmaf(xv.x, S##l0.z, accL[i].z)))); \
      accL[i].w = fmaf(xv.w, S##l3.w, fmaf(xv.z, S##l2.w, fmaf(xv.y, S##l1.w, fmaf(xv.x, S##l0.w, accL[i].w)))); \
      accR[i].x = fmaf(xv.w, S##r3.x, fmaf(xv.z, S##r2.x, fmaf(xv.y, S##r1.x, fmaf(xv.x, S##r0.x, accR[i].x)))); \
      accR[i].y = fmaf(xv.w, S##r3.y, fmaf(xv.z, S##r2.y, fmaf(xv.y, S##r1.y, fmaf(xv.x, S##r0.y, accR[i].y)))); \
      accR[i].z = fmaf(xv.w, S##r3.z, fmaf(xv.z, S##r2.z, fmaf(xv.y, S##r1.z, fmaf(xv.x, S##r0.z, accR[i].z)))); \
      accR[i].w = fmaf(xv.w, S##r3.w, fmaf(xv.z, S##r2.w, fmaf(xv.y, S##r1.w, fmaf(xv.x, S##r0.w, accR[i].w)))); \
    }                                                                         \
  } while(0)

__global__ __launch_bounds__(256) void k_gemm2(const float* __restrict__ x,
    const float* __restrict__ wl, const float* __restrict__ wr,
    float* __restrict__ xl, float* __restrict__ xr, int nrows){
  __shared__ float4 xs[128][16];
  const int tid = threadIdx.x;
  const int tx = tid & 15, ty = tid >> 4;
  const int r0 = blockIdx.x * 128;
  const int c0 = blockIdx.y * 64 + tx * 4;
  const float4* x4 = reinterpret_cast<const float4*>(x);
  float4 accL[8], accR[8];           // [row i] -> 4 cols
  #pragma unroll
  for (int i=0;i<8;i++){
    accL[i] = make_float4(0.f,0.f,0.f,0.f);
    accR[i] = make_float4(0.f,0.f,0.f,0.f);
  }
  const int swz = ty & 3;
  for (int kk = 0; kk < 128; kk += 64){
    if (kk) __syncthreads();
    #pragma unroll
    for (int it = 0; it < 8; ++it){
      int idx = tid + it*256;
      int r = idx >> 4, k4 = idx & 15;
      float4 v = make_float4(0.f,0.f,0.f,0.f);
      if (r0 + r < nrows) v = x4[(size_t)(r0+r)*32 + (kk>>2) + k4];
      xs[r][k4 ^ ((r>>3)&3)] = v;
    }
    __syncthreads();
    const float* wlp = wl + (size_t)kk*128 + c0;
    const float* wrp = wr + (size_t)kk*128 + c0;
    float4 Al0, Al1, Al2, Al3, Ar0, Ar1, Ar2, Ar3;
    float4 Bl0, Bl1, Bl2, Bl3, Br0, Br1, Br2, Br3;
    LOADW(A, 0);                       // prologue: set A <- k4=0
    for (int k4 = 0; k4 < 16; k4 += 2){
      LOADW(B, k4+1);                  // issue loads for odd step
      FMABLK(A, k4 ^ swz);             // compute even step (A ready)
      if (k4 + 2 < 16) LOADW(A, k4+2); // issue loads for next even step
      FMABLK(B, (k4+1) ^ swz);         // compute odd step (B in flight->ready)
    }
  }
  #pragma unroll
  for (int i = 0; i < 8; ++i){
    int row = r0 + ty*8 + i;
    if (row < nrows){
      *reinterpret_cast<float4*>(&xl[(size_t)row*128 + c0]) = accL[i];
      *reinterpret_cast<float4*>(&xr[(size_t)row*128 + c0]) = accR[i];
    }
  }
}

// ---------------- GATv2 edge pass: one wave per dst node, 4 edges/iter ----
// Edge slot egrp = lane>>4 (4 edges in flight); lane ql = lane&15 owns dims
// 8ql..8ql+7 (2 float4 gathers). Head h = ql>>1 spans 2 lanes -> 1 shfl_xor.
// Edge indices come from ONE coalesced load of 64 per chunk, distributed via
// __shfl (no dependent s_load chain). Next iteration's 2 gathers prefetched
// before current compute (1-deep pipeline). Softmax in log2 domain with
// defer-max (THR=8); flash-merge of 4 edge-slot states at the end.
__global__ __launch_bounds__(256) void k_gat(const float* __restrict__ xl,
    const float* __restrict__ xr, const int* __restrict__ row_ptr,
    const int* __restrict__ srcs, const float* __restrict__ att,
    const float* __restrict__ bias, float* __restrict__ xout, int n){
  int wid  = (blockIdx.x * blockDim.x + threadIdx.x) >> 6;
  int lane = threadIdx.x & 63;
  if (wid >= n) return;
  const int egrp = lane >> 4;
  const int ql   = lane & 15;
  const float4* xl4 = reinterpret_cast<const float4*>(xl);
  float4 xr0 = reinterpret_cast<const float4*>(xr)[wid*32 + (ql<<1)];
  float4 xr1 = reinterpret_cast<const float4*>(xr)[wid*32 + (ql<<1) + 1];
  constexpr float L2E = 1.44269504f;
  float4 aw0 = reinterpret_cast<const float4*>(att)[(ql<<1)];
  float4 aw1 = reinterpret_cast<const float4*>(att)[(ql<<1) + 1];
  const float a0 = aw0.x*L2E, a1 = aw0.y*L2E, a2 = aw0.z*L2E, a3 = aw0.w*L2E;
  const float a4 = aw1.x*L2E, a5 = aw1.y*L2E, a6 = aw1.z*L2E, a7 = aw1.w*L2E;
  float m = 0.f, ssum = 0.f;
  float ac0=0.f, ac1=0.f, ac2=0.f, ac3=0.f, ac4=0.f, ac5=0.f, ac6=0.f, ac7=0.f;
  const int start = row_ptr[wid], end = row_ptr[wid+1];
  for (int base = start; base < end; base += 64){
    int cnt = end - base; if (cnt > 64) cnt = 64;
    int sv = (lane < cnt) ? srcs[base + lane] : 0;
    int iters = (cnt + 3) >> 2;
    int sidx = __shfl(sv, egrp);
    float4 v0 = xl4[(size_t)sidx*32 + (ql<<1)];
    float4 v1 = xl4[(size_t)sidx*32 + (ql<<1) + 1];
    for (int t = 0; t < iters; ++t){
      float4 c0 = v0, c1 = v1;
      bool valid = ((t<<2) + egrp) < cnt;
      if (t + 1 < iters){
        int sj = __shfl(sv, ((t+1)<<2) + egrp);
        v0 = xl4[(size_t)sj*32 + (ql<<1)];
        v1 = xl4[(size_t)sj*32 + (ql<<1) + 1];
      }
      float e =       a0 * leaky(c0.x + xr0.x);
      e = fmaf(a1, leaky(c0.y + xr0.y), e);
      e = fmaf(a2, leaky(c0.z + xr0.z), e);
      e = fmaf(a3, leaky(c0.w + xr0.w), e);
      e = fmaf(a4, leaky(c1.x + xr1.x), e);
      e = fmaf(a5, leaky(c1.y + xr1.y), e);
      e = fmaf(a6, leaky(c1.z + xr1.z), e);
      e = fmaf(a7, leaky(c1.w + xr1.w), e);
      e += __shfl_xor(e, 1);                 // full head score in both lanes
      if (!valid) e = -INFINITY;
      if (__any(e - m > 8.f)){               // rare rescale
        float mn = fmaxf(m, e);
        float sc = __builtin_amdgcn_exp2f(m - mn);
        ssum *= sc;
        ac0 *= sc; ac1 *= sc; ac2 *= sc; ac3 *= sc;
        ac4 *= sc; ac5 *= sc; ac6 *= sc; ac7 *= sc;
        m = mn;
      }
      float pr = __builtin_amdgcn_exp2f(e - m);   // 0 for invalid (e=-inf)
      ssum += pr;
      ac0 = fmaf(pr, c0.x, ac0);  ac1 = fmaf(pr, c0.y, ac1);
      ac2 = fmaf(pr, c0.z, ac2);  ac3 = fmaf(pr, c0.w, ac3);
      ac4 = fmaf(pr, c1.x, ac4);  ac5 = fmaf(pr, c1.y, ac5);
      ac6 = fmaf(pr, c1.z, ac6);  ac7 = fmaf(pr, c1.w, ac7);
    }
  }
  // flash-merge the 4 edge-slot partial states (same dims, disjoint edges)
  #pragma unroll
  for (int w = 16; w <= 32; w <<= 1){
    float mo = __shfl_xor(m, w);
    float so = __shfl_xor(ssum, w);
    float b0 = __shfl_xor(ac0, w), b1 = __shfl_xor(ac1, w);
    float b2 = __shfl_xor(ac2, w), b3 = __shfl_xor(ac3, w);
    float b4 = __shfl_xor(ac4, w), b5 = __shfl_xor(ac5, w);
    float b6 = __shfl_xor(ac6, w), b7 = __shfl_xor(ac7, w);
    float mm = fmaxf(m, mo);
    float sa = __builtin_amdgcn_exp2f(m - mm);
    float sb = __builtin_amdgcn_exp2f(mo - mm);
    ssum = ssum*sa + so*sb;
    ac0 = ac0*sa + b0*sb;  ac1 = ac1*sa + b1*sb;
    ac2 = ac2*sa + b2*sb;  ac3 = ac3*sa + b3*sb;
    ac4 = ac4*sa + b4*sb;  ac5 = ac5*sa + b5*sb;
    ac6 = ac6*sa + b6*sb;  ac7 = ac7*sa + b7*sb;
    m = mm;
  }
  float inv = (end > start) ? 1.f/ssum : 0.f;
  const float4* b4p = reinterpret_cast<const float4*>(bias);
  if (egrp == 0){
    float4 bv = b4p[(ql<<1)];
    float4 o = make_float4(elu1(fmaf(ac0, inv, bv.x)), elu1(fmaf(ac1, inv, bv.y)),
                           elu1(fmaf(ac2, inv, bv.z)), elu1(fmaf(ac3, inv, bv.w)));
    reinterpret_cast<float4*>(xout)[wid*32 + (ql<<1)] = o;
  } else if (egrp == 1){
    float4 bv = b4p[(ql<<1) + 1];
    float4 o = make_float4(elu1(fmaf(ac4, inv, bv.x)), elu1(fmaf(ac5, inv, bv.y)),
                           elu1(fmaf(ac6, inv, bv.z)), elu1(fmaf(ac7, inv, bv.w)));
    reinterpret_cast<float4*>(xout)[wid*32 + (ql<<1) + 1] = o;
  }
}

// ---------------- graph node ranges (batch is sorted) ----------------
__global__ void k_graph_ptr(const int* __restrict__ batch, int* __restrict__ gp,
                            int n, int nb){
  int b = blockIdx.x*blockDim.x + threadIdx.x;
  if (b > nb) return;
  int lo = 0, hi = n;
  while (lo < hi){ int mid = (lo+hi)>>1; if (batch[mid] < b) lo = mid+1; else hi = mid; }
  gp[b] = lo;   // for b==nb this yields n
}

// ---------------- gated sum-pool + max-pool: one wave per graph ----------------
__global__ __launch_bounds__(256) void k_pool(const float* __restrict__ x,
    const int* __restrict__ gp, const float* __restrict__ read_w,
    const float* __restrict__ read_b, float* __restrict__ mol, int nb){
  int w    = (blockIdx.x * blockDim.x + threadIdx.x) >> 6;
  int lane = threadIdx.x & 63;
  if (w >= nb) return;
  const float2* x2 = reinterpret_cast<const float2*>(x);
  float rw0 = read_w[2*lane], rw1 = read_w[2*lane+1];
  float rb = read_b[0];
  float s0=0.f, s1=0.f, m0=-INFINITY, m1=-INFINITY;
  int start = gp[w], end = gp[w+1];
  for (int nidx = start; nidx < end; ++nidx){
    float2 v = x2[nidx*64 + lane];
    float d = v.x*rw0 + v.y*rw1;
    d += __shfl_xor(d, 1);  d += __shfl_xor(d, 2);  d += __shfl_xor(d, 4);
    d += __shfl_xor(d, 8);  d += __shfl_xor(d, 16); d += __shfl_xor(d, 32);
    float gate = 1.f/(1.f + expf(-(d + rb)));
    s0 += gate*v.x;  s1 += gate*v.y;
    m0 = fmaxf(m0, v.x);  m1 = fmaxf(m1, v.y);
  }
  if (end <= start){ m0 = 0.f; m1 = 0.f; }   // empty graph: isfinite guard
  mol[w*256 + 2*lane]       = s0;
  mol[w*256 + 2*lane+1]     = s1;
  mol[w*256 + 128 + 2*lane]   = m0;
  mol[w*256 + 128 + 2*lane+1] = m1;
}

// ---------------- Boltzmann + MLP head: one block (128 thr) per graph ----------------
__global__ __launch_bounds__(128) void k_head(const float* __restrict__ mol,
    const float* __restrict__ temps, const float* __restrict__ en_w,
    const float* __restrict__ en_b, const float* __restrict__ w1,
    const float* __restrict__ b1, const float* __restrict__ w2,
    const float* __restrict__ b2, float* __restrict__ out, int nb){
  __shared__ float molS[256];
  __shared__ float red[128];
  __shared__ float distS[128];
  __shared__ float hS[64];
  int b = blockIdx.x, tid = threadIdx.x;
  if (b >= nb) return;
  molS[tid]       = mol[b*256 + tid];
  molS[tid + 128] = mol[b*256 + 128 + tid];
  __syncthreads();
  float z = -INFINITY;
  if (tid < K){
    float acc = en_b[tid];
    for (int j=0;j<256;j++) acc += molS[j]*en_w[j*K + tid];
    z = -acc / temps[b];
  }
  red[tid] = z; __syncthreads();
  for (int off=64; off>0; off>>=1){
    if (tid < off) red[tid] = fmaxf(red[tid], red[tid+off]);
    __syncthreads();
  }
  float mx = red[0]; __syncthreads();
  float ex = (tid < K) ? expf(z - mx) : 0.f;
  red[tid] = ex; __syncthreads();
  for (int off=64; off>0; off>>=1){
    if (tid < off) red[tid] += red[tid+off];
    __syncthreads();
  }
  float denom = red[0];
  distS[tid] = ex / denom;
  __syncthreads();
  if (tid < 64){
    float acc = b1[tid];
    for (int k=0;k<K;k++) acc += distS[k]*w1[k*64 + tid];
    hS[tid] = elu1(acc);
  }
  __syncthreads();
  red[tid] = (tid < 64) ? hS[tid]*w2[tid] : 0.f;
  __syncthreads();
  for (int off=32; off>0; off>>=1){
    if (tid < off) red[tid] += red[tid+off];
    __syncthreads();
  }
  if (tid == 0) out[b] = red[0] + b2[0];
}

// ---------------- launch ----------------
extern "C" void kernel_launch(void* const* d_in, const int* in_sizes, int n_in,
                              void* d_out, int out_size, void* d_ws, size_t ws_size,
                              hipStream_t stream){
  const float* x0    = (const float*)d_in[0];
  const int*   ei    = (const int*)  d_in[1];
  const int*   batch = (const int*)  d_in[2];
  const float* temps = (const float*)d_in[3];
  const float* wl    = (const float*)d_in[4];
  const float* wr    = (const float*)d_in[5];
  const float* att   = (const float*)d_in[6];
  const float* gatb  = (const float*)d_in[7];
  const float* read_w= (const float*)d_in[8];
  const float* read_b= (const float*)d_in[9];
  const float* en_w  = (const float*)d_in[10];
  const float* en_b  = (const float*)d_in[11];
  const float* w1    = (const float*)d_in[12];
  const float* b1    = (const float*)d_in[13];
  const float* w2    = (const float*)d_in[14];
  const float* b2    = (const float*)d_in[15];
  float* out = (float*)d_out;

  const int N = in_sizes[0] / HID;
  const int E = in_sizes[1] / 2;
  const int B = in_sizes[3];
  const int* src = ei;
  const int* dst = ei + E;

  char* ws = (char*)d_ws;
  size_t off = 0;
  auto alloc = [&](size_t bytes)->char*{
    char* p = ws + off; off += (bytes + 255) & ~size_t(255); return p;
  };
  float* xl    = (float*)alloc(sizeof(float)*(size_t)N*HID);
  float* xr    = (float*)alloc(sizeof(float)*(size_t)N*HID);
  float* xb    = (float*)alloc(sizeof(float)*(size_t)N*HID);
  float* mol   = (float*)alloc(sizeof(float)*(size_t)B*2*HID);
  int* row_ptr = (int*)alloc(sizeof(int)*(size_t)(N+1));
  int* deg     = (int*)alloc(sizeof(int)*(size_t)N);
  int* fill    = (int*)alloc(sizeof(int)*(size_t)N);
  int* srcs    = (int*)alloc(sizeof(int)*(size_t)E);
  int* bsum    = (int*)alloc(sizeof(int)*1024);
  int* gp      = (int*)alloc(sizeof(int)*(size_t)(B+1));

  // --- CSR by dst (once per call; reused by all 4 layers) ---
  int nchunk = (N + 1023) / 1024;
  k_zero2<<<(N+255)/256, 256, 0, stream>>>(deg, fill, N);
  k_deg<<<(E+255)/256, 256, 0, stream>>>(dst, deg, E);
  k_scan1<<<nchunk, 256, 0, stream>>>(deg, row_ptr, bsum, N);
  k_scan2<<<1, 1, 0, stream>>>(bsum, nchunk);
  k_scan3<<<(N+255)/256, 256, 0, stream>>>(row_ptr, bsum, N);
  k_scatter<<<(E+255)/256, 256, 0, stream>>>(src, dst, row_ptr, fill, srcs, E);

  // --- 4 GATv2 layers ---
  const float* xin = x0;
  for (int l = 0; l < LAY; ++l){
    dim3 ggrid((N + 127)/128, 2);
    k_gemm2<<<ggrid, 256, 0, stream>>>(xin, wl + (size_t)l*HID*HID,
                                       wr + (size_t)l*HID*HID, xl, xr, N);
    k_gat<<<(N+3)/4, 256, 0, stream>>>(xl, xr, row_ptr, srcs,
                                       att + (size_t)l*H*DH, gatb + (size_t)l*HID, xb, N);
    xin = xb;
  }

  // --- readout + head ---
  k_graph_ptr<<<(B+1+255)/256, 256, 0, stream>>>(batch, gp, N, B);
  k_pool<<<(B+3)/4, 256, 0, stream>>>(xb, gp, read_w, read_b, mol, B);
  k_head<<<B, 128, 0, stream>>>(mol, temps, en_w, en_b, w1, b1, w2, b2, out, B);
}

// Round 6
// 966.195 us; speedup vs baseline: 1.7701x; 1.2844x over previous
//
#include <hip/hip_runtime.h>
#include <math.h>

// Model constants (shapes from reference)
static constexpr int HID = 128;
static constexpr int H   = 8;
static constexpr int DH  = 16;
static constexpr int LAY = 4;
static constexpr int K   = 100;

__device__ __forceinline__ float leaky(float x){ return fmaxf(x, 0.2f*x); }
__device__ __forceinline__ float elu1(float x){ return x > 0.f ? x : expm1f(x); }

typedef __attribute__((ext_vector_type(8))) short bf16x8;
typedef __attribute__((ext_vector_type(4))) float f32x4;

// RN-even float -> bf16 bits
__device__ __forceinline__ ushort f2bf(float f){
  uint u = __float_as_uint(f);
  u += 0x7FFFu + ((u >> 16) & 1u);
  return (ushort)(u >> 16);
}
__device__ __forceinline__ float bf2f(ushort h){ return __uint_as_float(((uint)h) << 16); }

// ---------------- utility ----------------
__global__ void k_zero2(int* p, int* q, int n){
  int i = blockIdx.x*blockDim.x + threadIdx.x;
  if (i < n){ p[i] = 0; q[i] = 0; }
}

// ---------------- CSR build (counting sort by dst) ----------------
__global__ void k_deg(const int* __restrict__ dst, int* __restrict__ deg, int E){
  int e = blockIdx.x*blockDim.x + threadIdx.x;
  if (e < E) atomicAdd(&deg[dst[e]], 1);
}

// chunked scan: 1024 elems/block, 256 threads x 4
__global__ void k_scan1(const int* __restrict__ deg, int* __restrict__ row_ptr,
                        int* __restrict__ bsum, int n){
  __shared__ int s[256];
  int tid = threadIdx.x;
  int base = blockIdx.x*1024 + tid*4;
  int v0 = (base+0 < n) ? deg[base+0] : 0;
  int v1 = (base+1 < n) ? deg[base+1] : 0;
  int v2 = (base+2 < n) ? deg[base+2] : 0;
  int v3 = (base+3 < n) ? deg[base+3] : 0;
  int t1 = v0+v1, t2 = t1+v2, t3 = t2+v3;
  s[tid] = t3;
  __syncthreads();
  for (int off=1; off<256; off<<=1){
    int t = (tid >= off) ? s[tid-off] : 0;
    __syncthreads();
    s[tid] += t;
    __syncthreads();
  }
  int excl = tid ? s[tid-1] : 0;
  if (base+0 < n) row_ptr[1+base+0] = excl + v0;
  if (base+1 < n) row_ptr[1+base+1] = excl + t1;
  if (base+2 < n) row_ptr[1+base+2] = excl + t2;
  if (base+3 < n) row_ptr[1+base+3] = excl + t3;
  if (tid == 255) bsum[blockIdx.x] = s[255];
}

__global__ void k_scan2(int* bsum, int nb){
  if (threadIdx.x == 0 && blockIdx.x == 0){
    int run = 0;
    for (int i=0;i<nb;i++){ int t = bsum[i]; bsum[i] = run; run += t; }
  }
}

__global__ void k_scan3(int* row_ptr, const int* __restrict__ bsum, int n){
  int i = blockIdx.x*blockDim.x + threadIdx.x;
  if (i < n) row_ptr[1+i] += bsum[i >> 10];
  if (i == 0) row_ptr[0] = 0;
}

__global__ void k_scatter(const int* __restrict__ src, const int* __restrict__ dst,
                          const int* __restrict__ row_ptr, int* __restrict__ fill,
                          int* __restrict__ srcs, int E){
  int e = blockIdx.x*blockDim.x + threadIdx.x;
  if (e < E){
    int d = dst[e];
    int pos = row_ptr[d] + atomicAdd(&fill[d], 1);
    srcs[pos] = src[e];
  }
}

// ---------------- W pre-pack into MFMA B-fragment order ----------------
// Layout: [layer][mat][hl][kk(4)][ntile(8)][lane(64)][j(8)] bf16.
// Fragment convention (16x16x32): col n = lane&15, k = kk*32 + (lane>>4)*8 + j.
// hl=0: bf16(w); hl=1: bf16(w - bf16(w)) residual.
__global__ void k_packw(const float* __restrict__ wl, const float* __restrict__ wr,
                        ushort* __restrict__ wpk){
  int tid = blockIdx.x*blockDim.x + threadIdx.x;
  if (tid >= LAY*2*2*4*8*64) return;
  int lane = tid & 63;
  int t = tid >> 6;
  int ntile = t & 7;  t >>= 3;
  int kk    = t & 3;  t >>= 2;
  int hl    = t & 1;  t >>= 1;
  int mat   = t & 1;  t >>= 1;
  int layer = t;
  const float* w = (mat ? wr : wl) + (size_t)layer*HID*HID;
  int n  = (ntile<<4) + (lane & 15);
  int kb = (kk<<5) + ((lane>>4)<<3);
  ushort o[8];
  #pragma unroll
  for (int j=0;j<8;j++){
    float v = w[(size_t)(kb+j)*HID + n];
    ushort hi = f2bf(v);
    o[j] = hl ? f2bf(v - bf2f(hi)) : hi;
  }
  ushort4* dstp = reinterpret_cast<ushort4*>(wpk + (size_t)tid*8);
  dstp[0] = make_ushort4(o[0],o[1],o[2],o[3]);
  dstp[1] = make_ushort4(o[4],o[5],o[6],o[7]);
}

// ---------------- fused xl/xr MFMA GEMM: [N,128] @ [128,128] x2 ----------
// bf16x2-split emulation: X=Xh+Xl, W=Wh+Wl; out = Xh*Wh + Xh*Wl + Xl*Wh
// (dropped Xl*Wl ~ 2^-18 relative). Block = 256 thr = 4 waves, M=64 rows,
// full N=128 for BOTH mats. Wave wv owns cols [wv*32, wv*32+32) of each mat.
// X staged in LDS as bf16 hi/lo [64][128] with XOR swizzle byte^=(row&7)<<4
// -> ds_read_b128 fragments are <=2-way (free). W read from packed fragments
// (L1/L2-resident, 16B/lane coalesced). A and B use the same k<->(g,j) map,
// so the result is invariant to the HW's internal k wiring.
__global__ __launch_bounds__(256) void k_gemm2m(const float* __restrict__ x,
    const ushort* __restrict__ wpk,   // this layer: [mat][hl][kk][ntile][lane][8]
    float* __restrict__ xl, float* __restrict__ xr, int nrows){
  __shared__ __align__(16) ushort Xh[64*128];
  __shared__ __align__(16) ushort Xlo[64*128];
  const int tid = threadIdx.x;
  const int r0 = blockIdx.x * 64;
  const float4* x4 = reinterpret_cast<const float4*>(x);
  #pragma unroll
  for (int it = 0; it < 8; ++it){
    int idx = tid + it*256;            // 2048 float4s = 64 rows x 32
    int r = idx >> 5, k4 = idx & 31;
    float4 v = make_float4(0.f,0.f,0.f,0.f);
    if (r0 + r < nrows) v = x4[(size_t)(r0+r)*32 + k4];
    ushort h0=f2bf(v.x), h1=f2bf(v.y), h2=f2bf(v.z), h3=f2bf(v.w);
    ushort l0=f2bf(v.x-bf2f(h0)), l1=f2bf(v.y-bf2f(h1)),
           l2=f2bf(v.z-bf2f(h2)), l3=f2bf(v.w-bf2f(h3));
    int baddr = r*256 + ((k4*8) ^ ((r&7)<<4));
    *reinterpret_cast<ushort4*>(reinterpret_cast<char*>(Xh)  + baddr) = make_ushort4(h0,h1,h2,h3);
    *reinterpret_cast<ushort4*>(reinterpret_cast<char*>(Xlo) + baddr) = make_ushort4(l0,l1,l2,l3);
  }
  __syncthreads();
  const int wv = tid >> 6, lane = tid & 63;
  const int arow = lane & 15;        // A-fragment row within 16-tile
  const int g    = lane >> 4;        // k-group
  f32x4 acc[4][2][2];                // [m-tile][n-tile][mat]
  #pragma unroll
  for (int m=0;m<4;m++)
    #pragma unroll
    for (int nti=0;nti<2;nti++)
      #pragma unroll
      for (int mt=0;mt<2;mt++)
        acc[m][nti][mt] = (f32x4){0.f,0.f,0.f,0.f};
  #pragma unroll
  for (int kk=0; kk<4; ++kk){
    bf16x8 ah[4], al[4];
    #pragma unroll
    for (int m=0;m<4;m++){
      int row = (m<<4) + arow;
      int boff = row*256 + (((kk<<6) + (g<<4)) ^ ((row&7)<<4));
      ah[m] = *reinterpret_cast<bf16x8*>(reinterpret_cast<char*>(Xh)  + boff);
      al[m] = *reinterpret_cast<bf16x8*>(reinterpret_cast<char*>(Xlo) + boff);
    }
    bf16x8 bfr[2][2][2];               // [mat][hl][nti]
    #pragma unroll
    for (int mt=0;mt<2;mt++)
      #pragma unroll
      for (int hl=0;hl<2;hl++)
        #pragma unroll
        for (int nti=0;nti<2;nti++){
          int nt = (wv<<1) + nti;
          size_t off = ((((size_t)(mt*2+hl)*4 + kk)*8 + nt)*64 + lane)*8;
          bfr[mt][hl][nti] = *reinterpret_cast<const bf16x8*>(wpk + off);
        }
    #pragma unroll
    for (int m=0;m<4;m++)
      #pragma unroll
      for (int nti=0;nti<2;nti++)
        #pragma unroll
        for (int mt=0;mt<2;mt++){
          f32x4 c = acc[m][nti][mt];
          c = __builtin_amdgcn_mfma_f32_16x16x32_bf16(ah[m], bfr[mt][0][nti], c, 0,0,0);
          c = __builtin_amdgcn_mfma_f32_16x16x32_bf16(ah[m], bfr[mt][1][nti], c, 0,0,0);
          c = __builtin_amdgcn_mfma_f32_16x16x32_bf16(al[m], bfr[mt][0][nti], c, 0,0,0);
          acc[m][nti][mt] = c;
        }
  }
  // epilogue: C/D layout col=lane&15, row=(lane>>4)*4+reg [HW-verified]
  const int orow = (lane >> 4) << 2;
  const int ocol = lane & 15;
  #pragma unroll
  for (int m=0;m<4;m++){
    #pragma unroll
    for (int nti=0;nti<2;nti++){
      int col = (((wv<<1) + nti)<<4) + ocol;
      #pragma unroll
      for (int r=0;r<4;r++){
        int row = r0 + (m<<4) + orow + r;
        if (row < nrows){
          xl[(size_t)row*HID + col] = acc[m][nti][0][r];
          xr[(size_t)row*HID + col] = acc[m][nti][1][r];
        }
      }
    }
  }
}

// ---------------- GATv2 edge pass: one wave per dst node, 4 edges/iter ----
// Edge slot egrp = lane>>4 (4 edges in flight); lane ql = lane&15 owns dims
// 8ql..8ql+7 (2 float4 gathers). Head h = ql>>1 spans 2 lanes -> 1 shfl_xor.
// Edge indices come from ONE coalesced load of 64 per chunk, distributed via
// __shfl (no dependent s_load chain). Next iteration's 2 gathers prefetched
// before current compute (1-deep pipeline). Softmax in log2 domain with
// defer-max (THR=8); flash-merge of 4 edge-slot states at the end.
__global__ __launch_bounds__(256) void k_gat(const float* __restrict__ xl,
    const float* __restrict__ xr, const int* __restrict__ row_ptr,
    const int* __restrict__ srcs, const float* __restrict__ att,
    const float* __restrict__ bias, float* __restrict__ xout, int n){
  int wid  = (blockIdx.x * blockDim.x + threadIdx.x) >> 6;
  int lane = threadIdx.x & 63;
  if (wid >= n) return;
  const int egrp = lane >> 4;
  const int ql   = lane & 15;
  const float4* xl4 = reinterpret_cast<const float4*>(xl);
  float4 xr0 = reinterpret_cast<const float4*>(xr)[wid*32 + (ql<<1)];
  float4 xr1 = reinterpret_cast<const float4*>(xr)[wid*32 + (ql<<1) + 1];
  constexpr float L2E = 1.44269504f;
  float4 aw0 = reinterpret_cast<const float4*>(att)[(ql<<1)];
  float4 aw1 = reinterpret_cast<const float4*>(att)[(ql<<1) + 1];
  const float a0 = aw0.x*L2E, a1 = aw0.y*L2E, a2 = aw0.z*L2E, a3 = aw0.w*L2E;
  const float a4 = aw1.x*L2E, a5 = aw1.y*L2E, a6 = aw1.z*L2E, a7 = aw1.w*L2E;
  float m = 0.f, ssum = 0.f;
  float ac0=0.f, ac1=0.f, ac2=0.f, ac3=0.f, ac4=0.f, ac5=0.f, ac6=0.f, ac7=0.f;
  const int start = row_ptr[wid], end = row_ptr[wid+1];
  for (int base = start; base < end; base += 64){
    int cnt = end - base; if (cnt > 64) cnt = 64;
    int sv = (lane < cnt) ? srcs[base + lane] : 0;
    int iters = (cnt + 3) >> 2;
    int sidx = __shfl(sv, egrp);
    float4 v0 = xl4[(size_t)sidx*32 + (ql<<1)];
    float4 v1 = xl4[(size_t)sidx*32 + (ql<<1) + 1];
    for (int t = 0; t < iters; ++t){
      float4 c0 = v0, c1 = v1;
      bool valid = ((t<<2) + egrp) < cnt;
      if (t + 1 < iters){
        int sj = __shfl(sv, ((t+1)<<2) + egrp);
        v0 = xl4[(size_t)sj*32 + (ql<<1)];
        v1 = xl4[(size_t)sj*32 + (ql<<1) + 1];
      }
      float e =       a0 * leaky(c0.x + xr0.x);
      e = fmaf(a1, leaky(c0.y + xr0.y), e);
      e = fmaf(a2, leaky(c0.z + xr0.z), e);
      e = fmaf(a3, leaky(c0.w + xr0.w), e);
      e = fmaf(a4, leaky(c1.x + xr1.x), e);
      e = fmaf(a5, leaky(c1.y + xr1.y), e);
      e = fmaf(a6, leaky(c1.z + xr1.z), e);
      e = fmaf(a7, leaky(c1.w + xr1.w), e);
      e += __shfl_xor(e, 1);                 // full head score in both lanes
      if (!valid) e = -INFINITY;
      if (__any(e - m > 8.f)){               // rare rescale
        float mn = fmaxf(m, e);
        float sc = __builtin_amdgcn_exp2f(m - mn);
        ssum *= sc;
        ac0 *= sc; ac1 *= sc; ac2 *= sc; ac3 *= sc;
        ac4 *= sc; ac5 *= sc; ac6 *= sc; ac7 *= sc;
        m = mn;
      }
      float pr = __builtin_amdgcn_exp2f(e - m);   // 0 for invalid (e=-inf)
      ssum += pr;
      ac0 = fmaf(pr, c0.x, ac0);  ac1 = fmaf(pr, c0.y, ac1);
      ac2 = fmaf(pr, c0.z, ac2);  ac3 = fmaf(pr, c0.w, ac3);
      ac4 = fmaf(pr, c1.x, ac4);  ac5 = fmaf(pr, c1.y, ac5);
      ac6 = fmaf(pr, c1.z, ac6);  ac7 = fmaf(pr, c1.w, ac7);
    }
  }
  // flash-merge the 4 edge-slot partial states (same dims, disjoint edges)
  #pragma unroll
  for (int w = 16; w <= 32; w <<= 1){
    float mo = __shfl_xor(m, w);
    float so = __shfl_xor(ssum, w);
    float b0 = __shfl_xor(ac0, w), b1 = __shfl_xor(ac1, w);
    float b2 = __shfl_xor(ac2, w), b3 = __shfl_xor(ac3, w);
    float b4 = __shfl_xor(ac4, w), b5 = __shfl_xor(ac5, w);
    float b6 = __shfl_xor(ac6, w), b7 = __shfl_xor(ac7, w);
    float mm = fmaxf(m, mo);
    float sa = __builtin_amdgcn_exp2f(m - mm);
    float sb = __builtin_amdgcn_exp2f(mo - mm);
    ssum = ssum*sa + so*sb;
    ac0 = ac0*sa + b0*sb;  ac1 = ac1*sa + b1*sb;
    ac2 = ac2*sa + b2*sb;  ac3 = ac3*sa + b3*sb;
    ac4 = ac4*sa + b4*sb;  ac5 = ac5*sa + b5*sb;
    ac6 = ac6*sa + b6*sb;  ac7 = ac7*sa + b7*sb;
    m = mm;
  }
  float inv = (end > start) ? 1.f/ssum : 0.f;
  const float4* b4p = reinterpret_cast<const float4*>(bias);
  if (egrp == 0){
    float4 bv = b4p[(ql<<1)];
    float4 o = make_float4(elu1(fmaf(ac0, inv, bv.x)), elu1(fmaf(ac1, inv, bv.y)),
                           elu1(fmaf(ac2, inv, bv.z)), elu1(fmaf(ac3, inv, bv.w)));
    reinterpret_cast<float4*>(xout)[wid*32 + (ql<<1)] = o;
  } else if (egrp == 1){
    float4 bv = b4p[(ql<<1) + 1];
    float4 o = make_float4(elu1(fmaf(ac4, inv, bv.x)), elu1(fmaf(ac5, inv, bv.y)),
                           elu1(fmaf(ac6, inv, bv.z)), elu1(fmaf(ac7, inv, bv.w)));
    reinterpret_cast<float4*>(xout)[wid*32 + (ql<<1) + 1] = o;
  }
}

// ---------------- graph node ranges (batch is sorted) ----------------
__global__ void k_graph_ptr(const int* __restrict__ batch, int* __restrict__ gp,
                            int n, int nb){
  int b = blockIdx.x*blockDim.x + threadIdx.x;
  if (b > nb) return;
  int lo = 0, hi = n;
  while (lo < hi){ int mid = (lo+hi)>>1; if (batch[mid] < b) lo = mid+1; else hi = mid; }
  gp[b] = lo;   // for b==nb this yields n
}

// ---------------- gated sum-pool + max-pool: one wave per graph ----------------
__global__ __launch_bounds__(256) void k_pool(const float* __restrict__ x,
    const int* __restrict__ gp, const float* __restrict__ read_w,
    const float* __restrict__ read_b, float* __restrict__ mol, int nb){
  int w    = (blockIdx.x * blockDim.x + threadIdx.x) >> 6;
  int lane = threadIdx.x & 63;
  if (w >= nb) return;
  const float2* x2 = reinterpret_cast<const float2*>(x);
  float rw0 = read_w[2*lane], rw1 = read_w[2*lane+1];
  float rb = read_b[0];
  float s0=0.f, s1=0.f, m0=-INFINITY, m1=-INFINITY;
  int start = gp[w], end = gp[w+1];
  for (int nidx = start; nidx < end; ++nidx){
    float2 v = x2[nidx*64 + lane];
    float d = v.x*rw0 + v.y*rw1;
    d += __shfl_xor(d, 1);  d += __shfl_xor(d, 2);  d += __shfl_xor(d, 4);
    d += __shfl_xor(d, 8);  d += __shfl_xor(d, 16); d += __shfl_xor(d, 32);
    float gate = 1.f/(1.f + expf(-(d + rb)));
    s0 += gate*v.x;  s1 += gate*v.y;
    m0 = fmaxf(m0, v.x);  m1 = fmaxf(m1, v.y);
  }
  if (end <= start){ m0 = 0.f; m1 = 0.f; }   // empty graph: isfinite guard
  mol[w*256 + 2*lane]       = s0;
  mol[w*256 + 2*lane+1]     = s1;
  mol[w*256 + 128 + 2*lane]   = m0;
  mol[w*256 + 128 + 2*lane+1] = m1;
}

// ---------------- Boltzmann + MLP head: one block (128 thr) per graph ----------------
__global__ __launch_bounds__(128) void k_head(const float* __restrict__ mol,
    const float* __restrict__ temps, const float* __restrict__ en_w,
    const float* __restrict__ en_b, const float* __restrict__ w1,
    const float* __restrict__ b1, const float* __restrict__ w2,
    const float* __restrict__ b2, float* __restrict__ out, int nb){
  __shared__ float molS[256];
  __shared__ float red[128];
  __shared__ float distS[128];
  __shared__ float hS[64];
  int b = blockIdx.x, tid = threadIdx.x;
  if (b >= nb) return;
  molS[tid]       = mol[b*256 + tid];
  molS[tid + 128] = mol[b*256 + 128 + tid];
  __syncthreads();
  float z = -INFINITY;
  if (tid < K){
    float acc = en_b[tid];
    for (int j=0;j<256;j++) acc += molS[j]*en_w[j*K + tid];
    z = -acc / temps[b];
  }
  red[tid] = z; __syncthreads();
  for (int off=64; off>0; off>>=1){
    if (tid < off) red[tid] = fmaxf(red[tid], red[tid+off]);
    __syncthreads();
  }
  float mx = red[0]; __syncthreads();
  float ex = (tid < K) ? expf(z - mx) : 0.f;
  red[tid] = ex; __syncthreads();
  for (int off=64; off>0; off>>=1){
    if (tid < off) red[tid] += red[tid+off];
    __syncthreads();
  }
  float denom = red[0];
  distS[tid] = ex / denom;
  __syncthreads();
  if (tid < 64){
    float acc = b1[tid];
    for (int k=0;k<K;k++) acc += distS[k]*w1[k*64 + tid];
    hS[tid] = elu1(acc);
  }
  __syncthreads();
  red[tid] = (tid < 64) ? hS[tid]*w2[tid] : 0.f;
  __syncthreads();
  for (int off=32; off>0; off>>=1){
    if (tid < off) red[tid] += red[tid+off];
    __syncthreads();
  }
  if (tid == 0) out[b] = red[0] + b2[0];
}

// ---------------- launch ----------------
extern "C" void kernel_launch(void* const* d_in, const int* in_sizes, int n_in,
                              void* d_out, int out_size, void* d_ws, size_t ws_size,
                              hipStream_t stream){
  const float* x0    = (const float*)d_in[0];
  const int*   ei    = (const int*)  d_in[1];
  const int*   batch = (const int*)  d_in[2];
  const float* temps = (const float*)d_in[3];
  const float* wl    = (const float*)d_in[4];
  const float* wr    = (const float*)d_in[5];
  const float* att   = (const float*)d_in[6];
  const float* gatb  = (const float*)d_in[7];
  const float* read_w= (const float*)d_in[8];
  const float* read_b= (const float*)d_in[9];
  const float* en_w  = (const float*)d_in[10];
  const float* en_b  = (const float*)d_in[11];
  const float* w1    = (const float*)d_in[12];
  const float* b1    = (const float*)d_in[13];
  const float* w2    = (const float*)d_in[14];
  const float* b2    = (const float*)d_in[15];
  float* out = (float*)d_out;

  const int N = in_sizes[0] / HID;
  const int E = in_sizes[1] / 2;
  const int B = in_sizes[3];
  const int* src = ei;
  const int* dst = ei + E;

  char* ws = (char*)d_ws;
  size_t off = 0;
  auto alloc = [&](size_t bytes)->char*{
    char* p = ws + off; off += (bytes + 255) & ~size_t(255); return p;
  };
  float* xl    = (float*)alloc(sizeof(float)*(size_t)N*HID);
  float* xr    = (float*)alloc(sizeof(float)*(size_t)N*HID);
  float* xb    = (float*)alloc(sizeof(float)*(size_t)N*HID);
  float* mol   = (float*)alloc(sizeof(float)*(size_t)B*2*HID);
  int* row_ptr = (int*)alloc(sizeof(int)*(size_t)(N+1));
  int* deg     = (int*)alloc(sizeof(int)*(size_t)N);
  int* fill    = (int*)alloc(sizeof(int)*(size_t)N);
  int* srcs    = (int*)alloc(sizeof(int)*(size_t)E);
  int* bsum    = (int*)alloc(sizeof(int)*1024);
  int* gp      = (int*)alloc(sizeof(int)*(size_t)(B+1));
  ushort* wpk  = (ushort*)alloc(sizeof(ushort)*(size_t)LAY*2*2*4*8*64*8);

  // --- CSR by dst (once per call; reused by all 4 layers) ---
  int nchunk = (N + 1023) / 1024;
  k_zero2<<<(N+255)/256, 256, 0, stream>>>(deg, fill, N);
  k_deg<<<(E+255)/256, 256, 0, stream>>>(dst, deg, E);
  k_scan1<<<nchunk, 256, 0, stream>>>(deg, row_ptr, bsum, N);
  k_scan2<<<1, 1, 0, stream>>>(bsum, nchunk);
  k_scan3<<<(N+255)/256, 256, 0, stream>>>(row_ptr, bsum, N);
  k_scatter<<<(E+255)/256, 256, 0, stream>>>(src, dst, row_ptr, fill, srcs, E);

  // --- pack W fragments (once per call) ---
  k_packw<<<(LAY*2*2*4*8*64 + 255)/256, 256, 0, stream>>>(wl, wr, wpk);

  // --- 4 GATv2 layers ---
  const float* xin = x0;
  for (int l = 0; l < LAY; ++l){
    k_gemm2m<<<(N+63)/64, 256, 0, stream>>>(xin, wpk + (size_t)l*2*2*4*8*64*8,
                                            xl, xr, N);
    k_gat<<<(N+3)/4, 256, 0, stream>>>(xl, xr, row_ptr, srcs,
                                       att + (size_t)l*H*DH, gatb + (size_t)l*HID, xb, N);
    xin = xb;
  }

  // --- readout + head ---
  k_graph_ptr<<<(B+1+255)/256, 256, 0, stream>>>(batch, gp, N, B);
  k_pool<<<(B+3)/4, 256, 0, stream>>>(xb, gp, read_w, read_b, mol, B);
  k_head<<<B, 128, 0, stream>>>(mol, temps, en_w, en_b, w1, b1, w2, b2, out, B);
}